// Round 10
// baseline (1787.430 us; speedup 1.0000x reference)
//
#include <hip/hip_runtime.h>
#include <hip/hip_bf16.h>
#include <stdint.h>

#define B 8
#define S 1024
#define L 1025
#define D 512
#define H 8
#define HD 64
#define NL 6
#define FF 2048
#define MAXD 64
#define OUTLEN 8
#define NC 10

#define MP 8320   // 65 * 128, padded M
#define VTL 1040  // vt row length (elems), 16B-aligned
#define MKL 1088  // maskf row length

typedef __bf16 bf16;
typedef __bf16 bf16x8 __attribute__((ext_vector_type(8)));
typedef __bf16 bf16x4 __attribute__((ext_vector_type(4)));
typedef float f32x4 __attribute__((ext_vector_type(4)));

__device__ __forceinline__ float fexp2(float x) { return __builtin_amdgcn_exp2f(x); }

__device__ __forceinline__ void gld16(const void* g, void* l) {
    __builtin_amdgcn_global_load_lds(
        (const __attribute__((address_space(1))) unsigned int*)g,
        (__attribute__((address_space(3))) unsigned int*)l,
        16, 0, 0);
}

// ---------------- f32 -> bf16 conversion (vectorized) ----------------
__global__ __launch_bounds__(256) void cvt_k(const float* __restrict__ in,
                                             bf16* __restrict__ out, int n4)
{
    int i = blockIdx.x * 256 + threadIdx.x;
    if (i >= n4) return;
    float4 v = reinterpret_cast<const float4*>(in)[i];
    bf16x4 o;
    o[0] = (bf16)v.x; o[1] = (bf16)v.y; o[2] = (bf16)v.z; o[3] = (bf16)v.w;
    reinterpret_cast<bf16x4*>(out)[i] = o;
}

// ---------------- embedding ----------------
__global__ void embed_k(const int* __restrict__ src, const float* __restrict__ emb,
                        const float* __restrict__ cls, float* __restrict__ x,
                        bf16* __restrict__ xb)
{
    long i = (long)blockIdx.x * blockDim.x + threadIdx.x; // over B*L*D
    if (i >= (long)B * L * D) return;
    int d = (int)(i % D);
    long bl = i / D;
    int l = (int)(bl % L);
    int b = (int)(bl / L);
    float v = (l == 0) ? cls[d] : emb[(long)src[b * S + (l - 1)] * D + d];
    x[i] = v;
    xb[i] = (bf16)v;
}

// ---------------- pad mask -> float table (layer-invariant) ----------------
__global__ void maskf_k(const unsigned char* __restrict__ pad, float* __restrict__ mf)
{
    int b = blockIdx.x;
    for (int k = threadIdx.x; k < MKL; k += 256) {
        float v;
        if (k == 0) v = 0.f;
        else if (k <= 1024) v = pad[b * S + k - 1] ? -1e9f : 0.f;
        else v = -1e9f;
        mf[b * MKL + k] = v;
    }
}

// ---------------- MFMA bf16 GEMM: C[MP,N] = A[MP,K] @ W[N,K]^T + bias ----------
// OBF: 0 = f32 out, 1 = bf16 out, 2 = qkv mode (Q/K -> Cb; V panel -> vt transposed)
template<int ACT, int OBF>
__global__ __launch_bounds__(256) void mgemm(const bf16* __restrict__ A,
                                             const bf16* __restrict__ W,
                                             const float* __restrict__ bias,
                                             float* __restrict__ Cf,
                                             bf16* __restrict__ Cb,
                                             bf16* __restrict__ vt,
                                             int N, int K)
{
    __shared__ bf16 Asl[128 * 32];
    __shared__ bf16 Bsl[128 * 32];
    int tid = threadIdx.x;
    int m0 = blockIdx.y * 128;
    int n0 = blockIdx.x * 128;
    int lane = tid & 63;
    int w = tid >> 6, wr = w >> 1, wc = w & 1;
    int wbase = tid & ~63;
    int kb = (lane >> 4) * 8;
    int rsel = lane & 15;
    f32x4 acc[4][4] = {};

    for (int k0 = 0; k0 < K; k0 += 32) {
#pragma unroll
        for (int r = 0; r < 2; r++) {
            int s = r * 256 + tid;
            int sb = r * 256 + wbase;
            gld16(A + (size_t)(m0 + (s >> 2)) * K + k0 + (s & 3) * 8, &Asl[(size_t)sb * 8]);
            gld16(W + (size_t)(n0 + (s >> 2)) * K + k0 + (s & 3) * 8, &Bsl[(size_t)sb * 8]);
        }
        __syncthreads();
        bf16x8 af[4], bfr[4];
#pragma unroll
        for (int fi = 0; fi < 4; fi++)
            af[fi] = *reinterpret_cast<const bf16x8*>(&Asl[(wr * 64 + fi * 16 + rsel) * 32 + kb]);
#pragma unroll
        for (int fj = 0; fj < 4; fj++)
            bfr[fj] = *reinterpret_cast<const bf16x8*>(&Bsl[(wc * 64 + fj * 16 + rsel) * 32 + kb]);
#pragma unroll
        for (int fi = 0; fi < 4; fi++)
#pragma unroll
            for (int fj = 0; fj < 4; fj++)
                acc[fi][fj] = __builtin_amdgcn_mfma_f32_16x16x32_bf16(af[fi], bfr[fj], acc[fi][fj], 0, 0, 0);
        __syncthreads();
    }
    int rowb = (lane >> 4) * 4;
    int colb = lane & 15;

    if (OBF == 2 && n0 >= 1024) {
        // V panel -> vt[((b*8+h)*64+d)*VTL + l], transposed
#pragma unroll
        for (int fi = 0; fi < 4; fi++) {
            int row0 = m0 + wr * 64 + fi * 16 + rowb;
            int bq[4], lq[4];
#pragma unroll
            for (int i = 0; i < 4; i++) {
                int r = row0 + i;
                int b_ = r / 1025;
                bq[i] = b_;
                lq[i] = r - b_ * 1025;
            }
#pragma unroll
            for (int fj = 0; fj < 4; fj++) {
                int col = n0 + wc * 64 + fj * 16 + colb;
                int cv = col - 1024;
                int hh = cv >> 6, dd = cv & 63;
                float bsv = bias[col];
#pragma unroll
                for (int i = 0; i < 4; i++) {
                    int r = row0 + i;
                    if (r < B * L)
                        vt[(size_t)((bq[i] * 8 + hh) * 64 + dd) * VTL + lq[i]] =
                            (bf16)(acc[fi][fj][i] + bsv);
                }
            }
        }
        return;
    }

#pragma unroll
    for (int fi = 0; fi < 4; fi++) {
#pragma unroll
        for (int fj = 0; fj < 4; fj++) {
            int col = n0 + wc * 64 + fj * 16 + colb;
            float bsv = bias[col];
#pragma unroll
            for (int i = 0; i < 4; i++) {
                int row = m0 + wr * 64 + fi * 16 + rowb + i;
                float v = acc[fi][fj][i] + bsv;
                if (ACT) v = 0.5f * v * (1.f + erff(v * 0.70710678118654752f));
                if (OBF) Cb[(size_t)row * N + col] = (bf16)v;
                else     Cf[(size_t)row * N + col] = v;
            }
        }
    }
}

// ---------------- MFMA flash attention v5: barrier-free ----------------
// Swapped QK^T (lane ln15 = q-row), O^T accumulation. K,Q,V fragments ALL
// direct from global (L2-resident; V pre-transposed by qkv GEMM). P in
// per-wave LDS. No __syncthreads in the main loop -> waves fully independent.
__global__ __launch_bounds__(256) void fattn_k(const bf16* __restrict__ qkv,
                                               const bf16* __restrict__ vt,
                                               const float* __restrict__ rel_emb_l,
                                               const float* __restrict__ maskf,
                                               bf16* __restrict__ ob)
{
    constexpr int PIT = 72;
    __shared__ bf16 Psh[4][16 * PIT];    // per-wave P[q][kv]
    __shared__ float bias2s[2 * MAXD + 1];

    const int bh = blockIdx.x;
    const int qt = blockIdx.y;
    const int h = bh & 7, b = bh >> 3;
    const int q0 = qt * 64;
    const int tid = threadIdx.x;
    const int lane = tid & 63;
    const int w = tid >> 6;
    const int ln15 = lane & 15, g4 = lane >> 4;
    const int kb8 = g4 * 8;
    constexpr float LOG2E = 1.4426950408889634f;
    constexpr float C2 = 0.125f * LOG2E;

    const char* base = (const char*)qkv + (size_t)(b * L) * 3072 + (size_t)h * (HD * 2);
    const char* vbase = (const char*)vt + (size_t)((b * 8 + h) * 64) * (VTL * 2);
    const float* mrow = maskf + b * MKL;

    for (int i = tid; i < 2 * MAXD + 1; i += 256) bias2s[i] = rel_emb_l[i * H + h] * LOG2E;
    __syncthreads();   // the only block-wide barrier (bias table)

    // Q fragments (B-frag of QK^T): lane holds Q[qrow][kb8..+7], [+32..]
    const int qrow = q0 + w * 16 + ln15;   // may exceed 1024: in-bounds garbage, store-guarded
    bf16x8 qa0 = *(const bf16x8*)(base + (size_t)qrow * 3072 + g4 * 16);
    bf16x8 qa1 = *(const bf16x8*)(base + (size_t)qrow * 3072 + 64 + g4 * 16);

    // K fragments tile 0 (A-frag: lane holds K[fj*16+ln15][kb8..+7])
    bf16x8 kr[4][2];
#pragma unroll
    for (int fj = 0; fj < 4; fj++) {
        const char* rp = base + (size_t)(fj * 16 + ln15) * 3072 + 1024 + g4 * 16;
        kr[fj][0] = *(const bf16x8*)(rp);
        kr[fj][1] = *(const bf16x8*)(rp + 64);
    }

    f32x4 oacc[4] = {};
    float m_prev = -1e30f, l_sum = 0.f;

    for (int t = 0; t < 17; t++) {
        const int k0 = t * 64;
        const int k0n = (k0 + 64 > 1024) ? 1024 : (k0 + 64);

        // A: V^T fragments for THIS tile, direct from global (hidden under QK^T+softmax)
        bf16x8 vfr[4][2];
#pragma unroll
        for (int fd = 0; fd < 4; fd++) {
            const char* vp = vbase + (size_t)(fd * 16 + ln15) * (VTL * 2) + k0 * 2 + g4 * 16;
            vfr[fd][0] = *(const bf16x8*)(vp);
            vfr[fd][1] = *(const bf16x8*)(vp + 64);
        }

        // B: S^T = K @ Q^T : lane holds kv = fj*16 + g4*4 + i, q = ln15
        f32x4 sacc[4] = {};
#pragma unroll
        for (int fj = 0; fj < 4; fj++) {
            sacc[fj] = __builtin_amdgcn_mfma_f32_16x16x32_bf16(kr[fj][0], qa0, sacc[fj], 0, 0, 0);
            sacc[fj] = __builtin_amdgcn_mfma_f32_16x16x32_bf16(kr[fj][1], qa1, sacc[fj], 0, 0, 0);
        }
        // prefetch K for t+1
#pragma unroll
        for (int fj = 0; fj < 4; fj++) {
            const char* rp = base + (size_t)(k0n + fj * 16 + ln15) * 3072 + 1024 + g4 * 16;
            kr[fj][0] = *(const bf16x8*)(rp);
            kr[fj][1] = *(const bf16x8*)(rp + 64);
        }

        // mask (float4 per fj) + scale + rel-bias (log2 domain)
        f32x4 mv[4];
#pragma unroll
        for (int fj = 0; fj < 4; fj++)
            mv[fj] = *(const f32x4*)&mrow[k0 + fj * 16 + g4 * 4];

        float sv[4][4];
        const int relbw = k0 - q0 - w * 16;    // wave-uniform
        if (relbw >= MAXD + 15 || relbw <= -MAXD - 63) {
            const float bu = bias2s[relbw > 0 ? 2 * MAXD : 0];
#pragma unroll
            for (int fj = 0; fj < 4; fj++)
#pragma unroll
                for (int i = 0; i < 4; i++)
                    sv[fj][i] = fmaf(sacc[fj][i], C2, bu + mv[fj][i]);
        } else {
            const int relb = k0 - qrow;
#pragma unroll
            for (int fj = 0; fj < 4; fj++)
#pragma unroll
                for (int i = 0; i < 4; i++) {
                    int rel = relb + fj * 16 + g4 * 4 + i;
                    rel = rel < -MAXD ? -MAXD : (rel > MAXD ? MAXD : rel);
                    sv[fj][i] = fmaf(sacc[fj][i], C2, bias2s[rel + MAXD] + mv[fj][i]);
                }
        }

        // online softmax: lane-local state for q=ln15; reduce across g4 (lanes ^16, ^32)
        float mx = sv[0][0];
#pragma unroll
        for (int fj = 0; fj < 4; fj++)
#pragma unroll
            for (int i = 0; i < 4; i++) mx = fmaxf(mx, sv[fj][i]);
        mx = fmaxf(mx, __shfl_xor(mx, 16));
        mx = fmaxf(mx, __shfl_xor(mx, 32));
        const float mnew = fmaxf(m_prev, mx);
        const float corr = fexp2(m_prev - mnew);
        float pb[4][4];
        float rsum = 0.f;
#pragma unroll
        for (int fj = 0; fj < 4; fj++)
#pragma unroll
            for (int i = 0; i < 4; i++) {
                float p = fexp2(sv[fj][i] - mnew);
                pb[fj][i] = p;
                rsum += p;
            }
        rsum += __shfl_xor(rsum, 16);
        rsum += __shfl_xor(rsum, 32);
        l_sum = l_sum * corr + rsum;
        m_prev = mnew;
#pragma unroll
        for (int fd = 0; fd < 4; fd++) oacc[fd] *= corr;

        // P -> per-wave LDS: Psh[q=ln15][kv], 8B packed writes (wave-private, no barrier)
#pragma unroll
        for (int fj = 0; fj < 4; fj++) {
            union { bf16 hh[4]; unsigned long long u; } pk;
            pk.hh[0] = (bf16)pb[fj][0]; pk.hh[1] = (bf16)pb[fj][1];
            pk.hh[2] = (bf16)pb[fj][2]; pk.hh[3] = (bf16)pb[fj][3];
            *(unsigned long long*)&Psh[w][ln15 * PIT + fj * 16 + g4 * 4] = pk.u;
        }

        // E: O^T += V^T @ P (A-frag = vfr from global, B-frag = P from per-wave LDS)
        bf16x8 pa0 = *(const bf16x8*)&Psh[w][ln15 * PIT + kb8];
        bf16x8 pa1 = *(const bf16x8*)&Psh[w][ln15 * PIT + 32 + kb8];
#pragma unroll
        for (int fd = 0; fd < 4; fd++) {
            oacc[fd] = __builtin_amdgcn_mfma_f32_16x16x32_bf16(vfr[fd][0], pa0, oacc[fd], 0, 0, 0);
            oacc[fd] = __builtin_amdgcn_mfma_f32_16x16x32_bf16(vfr[fd][1], pa1, oacc[fd], 0, 0, 0);
        }
    }

    // epilogue: lane holds O^T[d = fd*16 + g4*4 + i][q = ln15]; l_sum lane-local
    if (qrow < L) {
        const float inv = 1.f / l_sum;
        bf16* op = ob + (size_t)(b * L + qrow) * D + h * HD + g4 * 4;
#pragma unroll
        for (int fd = 0; fd < 4; fd++) {
            bf16x4 r;
#pragma unroll
            for (int i = 0; i < 4; i++) r[i] = (bf16)(oacc[fd][i] * inv);
            *(bf16x4*)(op + fd * 16) = r;
        }
    }
}

// ---------------- out = LayerNorm(xin + rin), f32 + bf16 copies ----------------
__global__ __launch_bounds__(256) void add_ln_k(const float* __restrict__ xin,
                                                const float* __restrict__ rin,
                                                const float* __restrict__ g,
                                                const float* __restrict__ bb,
                                                float* __restrict__ out,
                                                bf16* __restrict__ outb)
{
    int row = blockIdx.x;
    __shared__ float red[8];
    int tid = threadIdx.x;
    const float* xp = xin + (size_t)row * D;
    const float* rp = rin + (size_t)row * D;
    float v0 = xp[tid] + rp[tid];
    float v1 = xp[tid + 256] + rp[tid + 256];
    float s = v0 + v1;
    for (int off = 32; off; off >>= 1) s += __shfl_down(s, off, 64);
    int lane = tid & 63, wid = tid >> 6;
    if (lane == 0) red[wid] = s;
    __syncthreads();
    if (tid == 0) red[0] = red[0] + red[1] + red[2] + red[3];
    __syncthreads();
    float mean = red[0] * (1.f / D);
    float d0 = v0 - mean, d1 = v1 - mean;
    float sq = d0 * d0 + d1 * d1;
    for (int off = 32; off; off >>= 1) sq += __shfl_down(sq, off, 64);
    if (lane == 0) red[4 + wid] = sq;
    __syncthreads();
    if (tid == 0) red[4] = red[4] + red[5] + red[6] + red[7];
    __syncthreads();
    float rs = rsqrtf(red[4] * (1.f / D) + 1e-5f);
    float r0 = d0 * rs * g[tid] + bb[tid];
    float r1 = d1 * rs * g[tid + 256] + bb[tid + 256];
    out[(size_t)row * D + tid] = r0;
    out[(size_t)row * D + tid + 256] = r1;
    outb[(size_t)row * D + tid] = (bf16)r0;
    outb[(size_t)row * D + tid + 256] = (bf16)r1;
}

// ---------------- final LN (row 0 only) + classifier ----------------
__global__ __launch_bounds__(256) void cls_k(const float* __restrict__ x,
                                             const float* __restrict__ ng,
                                             const float* __restrict__ nb,
                                             const float* __restrict__ cw,
                                             const float* __restrict__ cb,
                                             float* __restrict__ out)
{
    int b = blockIdx.x;
    __shared__ float xn[D];
    __shared__ float red[8];
    int tid = threadIdx.x;
    const float* xp = x + (size_t)(b * L) * D;
    float v0 = xp[tid], v1 = xp[tid + 256];
    float s = v0 + v1;
    for (int off = 32; off; off >>= 1) s += __shfl_down(s, off, 64);
    int lane = tid & 63, wid = tid >> 6;
    if (lane == 0) red[wid] = s;
    __syncthreads();
    if (tid == 0) red[0] = red[0] + red[1] + red[2] + red[3];
    __syncthreads();
    float mean = red[0] * (1.f / D);
    float d0 = v0 - mean, d1 = v1 - mean;
    float sq = d0 * d0 + d1 * d1;
    for (int off = 32; off; off >>= 1) sq += __shfl_down(sq, off, 64);
    if (lane == 0) red[4 + wid] = sq;
    __syncthreads();
    if (tid == 0) red[4] = red[4] + red[5] + red[6] + red[7];
    __syncthreads();
    float rs = rsqrtf(red[4] * (1.f / D) + 1e-5f);
    xn[tid] = d0 * rs * ng[tid] + nb[tid];
    xn[tid + 256] = d1 * rs * ng[tid + 256] + nb[tid + 256];
    __syncthreads();
    for (int o = tid; o < OUTLEN * NC; o += 256) {
        float acc = cb[o];
        const float* wp = cw + (size_t)o * D;
        for (int d = 0; d < D; d++) acc += xn[d] * wp[d];
        out[b * OUTLEN * NC + o] = acc;
    }
}

extern "C" void kernel_launch(void* const* d_in, const int* in_sizes, int n_in,
                              void* d_out, int out_size, void* d_ws, size_t ws_size,
                              hipStream_t stream) {
    const int* src = (const int*)d_in[0];
    const unsigned char* pad = (const unsigned char*)d_in[1];
    const float* emb = (const float*)d_in[2];
    const float* cls_token = (const float*)d_in[3];
    const float* qkv_w = (const float*)d_in[4];
    const float* qkv_b = (const float*)d_in[5];
    const float* out_w = (const float*)d_in[6];
    const float* out_b = (const float*)d_in[7];
    const float* rel_emb = (const float*)d_in[8];
    const float* ln1_g = (const float*)d_in[9];
    const float* ln1_b = (const float*)d_in[10];
    const float* w1 = (const float*)d_in[11];
    const float* b1 = (const float*)d_in[12];
    const float* w2 = (const float*)d_in[13];
    const float* b2 = (const float*)d_in[14];
    const float* ln2_g = (const float*)d_in[15];
    const float* ln2_b = (const float*)d_in[16];
    const float* norm_g = (const float*)d_in[17];
    const float* norm_b = (const float*)d_in[18];
    const float* cls_w = (const float*)d_in[19];
    const float* cls_b = (const float*)d_in[20];
    float* out = (float*)d_out;

    char* ws = (char*)d_ws;
    size_t off = 0;
    float* x   = (float*)(ws + off); off += (size_t)MP * D * 4;
    bf16*  xb  = (bf16*) (ws + off); off += (size_t)MP * D * 2;
    float* x2  = (float*)(ws + off); off += (size_t)MP * D * 4;
    bf16*  x2b = (bf16*) (ws + off); off += (size_t)MP * D * 2;
    char*  R   = ws + off;           off += (size_t)MP * 3 * D * 4; // qkvb | (hb + p)
    bf16*  qkvb = (bf16*)R;                              // MP*3D*2
    bf16*  hb  = (bf16*)R;                               // MP*FF*2 (after attn)
    float* p   = (float*)(R + (size_t)MP * FF * 2);      // MP*D*4
    bf16*  obf = (bf16*) (ws + off); off += (size_t)MP * D * 2;
    bf16*  vt  = (bf16*) (ws + off); off += ((size_t)B * H * 64 * VTL + 64) * 2;
    float* mf  = (float*)(ws + off); off += (size_t)B * MKL * 4;

    const size_t WQ = (size_t)NL * 3 * D * D;
    const size_t WO = (size_t)NL * D * D;
    const size_t W1E = (size_t)NL * FF * D;
    const size_t W2E = (size_t)NL * D * FF;
    const size_t WALL = WQ + WO + W1E + W2E;
    bool all_w = (off + WALL * 2) <= ws_size;

    bf16 *wq_a = nullptr, *wo_a = nullptr, *w1_a = nullptr, *w2_a = nullptr, *wbuf = nullptr;
    if (all_w) {
        wq_a = (bf16*)(ws + off);
        wo_a = wq_a + WQ;
        w1_a = wo_a + WO;
        w2_a = w1_a + W1E;
        int n4;
        n4 = (int)(WQ / 4);  cvt_k<<<dim3((n4 + 255) / 256), 256, 0, stream>>>(qkv_w, wq_a, n4);
        n4 = (int)(WO / 4);  cvt_k<<<dim3((n4 + 255) / 256), 256, 0, stream>>>(out_w, wo_a, n4);
        n4 = (int)(W1E / 4); cvt_k<<<dim3((n4 + 255) / 256), 256, 0, stream>>>(w1, w1_a, n4);
        n4 = (int)(W2E / 4); cvt_k<<<dim3((n4 + 255) / 256), 256, 0, stream>>>(w2, w2_a, n4);
    } else {
        wbuf = (bf16*)(ws + off); // per-layer rotating buffer
    }

    const int M = B * L;
    {
        long total = (long)B * L * D;
        embed_k<<<dim3((unsigned)((total + 255) / 256)), 256, 0, stream>>>(src, emb, cls_token, x, xb);
        maskf_k<<<dim3(B), 256, 0, stream>>>(pad, mf);
    }
    for (int l = 0; l < NL; l++) {
        const float* qb  = qkv_b + (size_t)l * 3 * D;
        const float* obi = out_b + (size_t)l * D;
        const float* re  = rel_emb + (size_t)l * (2 * MAXD + 1) * H;
        const float* g1  = ln1_g + (size_t)l * D;
        const float* be1 = ln1_b + (size_t)l * D;
        const float* B1p = b1 + (size_t)l * FF;
        const float* B2p = b2 + (size_t)l * D;
        const float* g2  = ln2_g + (size_t)l * D;
        const float* be2 = ln2_b + (size_t)l * D;

        const bf16 *wqb, *wob, *w1b, *w2b;
        if (all_w) {
            wqb = wq_a + (size_t)l * 3 * D * D;
            wob = wo_a + (size_t)l * D * D;
            w1b = w1_a + (size_t)l * FF * D;
            w2b = w2_a + (size_t)l * D * FF;
        } else {
            bf16* wp_ = wbuf;
            wqb = wp_;            wp_ += 3 * D * D;
            wob = wp_;            wp_ += D * D;
            w1b = wp_;            wp_ += FF * D;
            w2b = wp_;
            int n4;
            n4 = 3 * D * D / 4; cvt_k<<<dim3((n4 + 255) / 256), 256, 0, stream>>>(qkv_w + (size_t)l * 3 * D * D, (bf16*)wqb, n4);
            n4 = D * D / 4;     cvt_k<<<dim3((n4 + 255) / 256), 256, 0, stream>>>(out_w + (size_t)l * D * D, (bf16*)wob, n4);
            n4 = FF * D / 4;    cvt_k<<<dim3((n4 + 255) / 256), 256, 0, stream>>>(w1 + (size_t)l * FF * D, (bf16*)w1b, n4);
            n4 = D * FF / 4;    cvt_k<<<dim3((n4 + 255) / 256), 256, 0, stream>>>(w2 + (size_t)l * D * FF, (bf16*)w2b, n4);
        }

        mgemm<0, 2><<<dim3(3 * D / 128, MP / 128), 256, 0, stream>>>(xb, wqb, qb, nullptr, qkvb, vt, 3 * D, D);
        fattn_k<<<dim3(B * H, (L + 63) / 64), 256, 0, stream>>>(qkvb, vt, re, mf, obf);
        mgemm<0, 0><<<dim3(D / 128, MP / 128), 256, 0, stream>>>(obf, wob, obi, p, nullptr, nullptr, D, D);
        add_ln_k<<<dim3(M), 256, 0, stream>>>(x, p, g1, be1, x2, x2b);
        mgemm<1, 1><<<dim3(FF / 128, MP / 128), 256, 0, stream>>>(x2b, w1b, B1p, nullptr, hb, nullptr, FF, D);
        mgemm<0, 0><<<dim3(D / 128, MP / 128), 256, 0, stream>>>(hb, w2b, B2p, p, nullptr, nullptr, D, FF);
        add_ln_k<<<dim3(M), 256, 0, stream>>>(x2, p, g2, be2, x, xb);
    }
    cls_k<<<dim3(B), 256, 0, stream>>>(x, norm_g, norm_b, cls_w, cls_b, out);
}

// Round 11
// 1782.269 us; speedup vs baseline: 1.0029x; 1.0029x over previous
//
#include <hip/hip_runtime.h>
#include <hip/hip_bf16.h>
#include <stdint.h>

#define B 8
#define S 1024
#define L 1025
#define D 512
#define H 8
#define HD 64
#define NL 6
#define FF 2048
#define MAXD 64
#define OUTLEN 8
#define NC 10

#define MP 8320   // 65 * 128, padded M

typedef __bf16 bf16;
typedef __bf16 bf16x8 __attribute__((ext_vector_type(8)));
typedef __bf16 bf16x4 __attribute__((ext_vector_type(4)));
typedef float f32x4 __attribute__((ext_vector_type(4)));

__device__ __forceinline__ float fexp2(float x) { return __builtin_amdgcn_exp2f(x); }

// barrier WITHOUT the vmcnt(0) drain: LDS ops drained, global prefetch stays in flight
#define LGKM_BARRIER() asm volatile("s_waitcnt lgkmcnt(0)\ns_barrier" ::: "memory")

__device__ __forceinline__ void gld16(const void* g, void* l) {
    __builtin_amdgcn_global_load_lds(
        (const __attribute__((address_space(1))) unsigned int*)g,
        (__attribute__((address_space(3))) unsigned int*)l,
        16, 0, 0);
}

// ---------------- f32 -> bf16 conversion (vectorized) ----------------
__global__ __launch_bounds__(256) void cvt_k(const float* __restrict__ in,
                                             bf16* __restrict__ out, int n4)
{
    int i = blockIdx.x * 256 + threadIdx.x;
    if (i >= n4) return;
    float4 v = reinterpret_cast<const float4*>(in)[i];
    bf16x4 o;
    o[0] = (bf16)v.x; o[1] = (bf16)v.y; o[2] = (bf16)v.z; o[3] = (bf16)v.w;
    reinterpret_cast<bf16x4*>(out)[i] = o;
}

// ---------------- embedding ----------------
__global__ void embed_k(const int* __restrict__ src, const float* __restrict__ emb,
                        const float* __restrict__ cls, float* __restrict__ x,
                        bf16* __restrict__ xb)
{
    long i = (long)blockIdx.x * blockDim.x + threadIdx.x; // over B*L*D
    if (i >= (long)B * L * D) return;
    int d = (int)(i % D);
    long bl = i / D;
    int l = (int)(bl % L);
    int b = (int)(bl / L);
    float v = (l == 0) ? cls[d] : emb[(long)src[b * S + (l - 1)] * D + d];
    x[i] = v;
    xb[i] = (bf16)v;
}

// ---------------- MFMA bf16 GEMM: C[MP,N] = A[MP,K] @ W[N,K]^T + bias ----------
template<int ACT, int OBF>
__global__ __launch_bounds__(256) void mgemm(const bf16* __restrict__ A,
                                             const bf16* __restrict__ W,
                                             const float* __restrict__ bias,
                                             float* __restrict__ Cf,
                                             bf16* __restrict__ Cb,
                                             int N, int K)
{
    __shared__ bf16 Asl[128 * 32];
    __shared__ bf16 Bsl[128 * 32];
    int tid = threadIdx.x;
    int m0 = blockIdx.y * 128;
    int n0 = blockIdx.x * 128;
    int lane = tid & 63;
    int w = tid >> 6, wr = w >> 1, wc = w & 1;
    int wbase = tid & ~63;
    int kb = (lane >> 4) * 8;
    int rsel = lane & 15;
    f32x4 acc[4][4] = {};

    for (int k0 = 0; k0 < K; k0 += 32) {
#pragma unroll
        for (int r = 0; r < 2; r++) {
            int s = r * 256 + tid;
            int sb = r * 256 + wbase;
            gld16(A + (size_t)(m0 + (s >> 2)) * K + k0 + (s & 3) * 8, &Asl[(size_t)sb * 8]);
            gld16(W + (size_t)(n0 + (s >> 2)) * K + k0 + (s & 3) * 8, &Bsl[(size_t)sb * 8]);
        }
        __syncthreads();
        bf16x8 af[4], bfr[4];
#pragma unroll
        for (int fi = 0; fi < 4; fi++)
            af[fi] = *reinterpret_cast<const bf16x8*>(&Asl[(wr * 64 + fi * 16 + rsel) * 32 + kb]);
#pragma unroll
        for (int fj = 0; fj < 4; fj++)
            bfr[fj] = *reinterpret_cast<const bf16x8*>(&Bsl[(wc * 64 + fj * 16 + rsel) * 32 + kb]);
#pragma unroll
        for (int fi = 0; fi < 4; fi++)
#pragma unroll
            for (int fj = 0; fj < 4; fj++)
                acc[fi][fj] = __builtin_amdgcn_mfma_f32_16x16x32_bf16(af[fi], bfr[fj], acc[fi][fj], 0, 0, 0);
        __syncthreads();
    }
    int rowb = (lane >> 4) * 4;
    int colb = lane & 15;
#pragma unroll
    for (int fi = 0; fi < 4; fi++) {
#pragma unroll
        for (int fj = 0; fj < 4; fj++) {
            int col = n0 + wc * 64 + fj * 16 + colb;
            float bsv = bias[col];
#pragma unroll
            for (int i = 0; i < 4; i++) {
                int row = m0 + wr * 64 + fi * 16 + rowb + i;
                float v = acc[fi][fj][i] + bsv;
                if (ACT) v = 0.5f * v * (1.f + erff(v * 0.70710678118654752f));
                if (OBF) Cb[(size_t)row * N + col] = (bf16)v;
                else     Cf[(size_t)row * N + col] = v;
            }
        }
    }
}

// ---------------- MFMA flash attention v6: 8 waves / 128-row q-tile ----------
// Same per-wave structure as the verified v4 (R9): swapped QK^T, lane-local
// softmax, LDS Vt double-buffer + XOR swizzle, lgkm-only barriers. Twice the
// waves per block to raise resident-wave count (latency hiding).
__global__ __launch_bounds__(512) void fattn_k(const bf16* __restrict__ qkv,
                                               const float* __restrict__ rel_emb_l,
                                               const unsigned char* __restrict__ pad,
                                               bf16* __restrict__ ob)
{
    constexpr int PIT = 72;              // row pitch (bf16); 144 B = 9*16 -> b128-aligned rows
    __shared__ bf16 Vt[2][64 * PIT];     // V^T[d][k ^ ((d>>3)<<3)]
    __shared__ bf16 Psh[8][16 * PIT];    // per-wave P[q][kv]
    __shared__ float bias2s[2 * MAXD + 1];
    __shared__ float colm[2][64];

    const int bh = blockIdx.x;
    const int qt = blockIdx.y;
    const int h = bh & 7, b = bh >> 3;
    const int q0 = qt * 128;
    const int tid = threadIdx.x;
    const int lane = tid & 63;
    const int w = tid >> 6;              // 0..7
    const int ln15 = lane & 15, g4 = lane >> 4;
    const int kb8 = g4 * 8;
    constexpr float LOG2E = 1.4426950408889634f;
    constexpr float C2 = 0.125f * LOG2E;

    const char* base = (const char*)qkv + (size_t)(b * L) * 3072 + (size_t)h * (HD * 2);

    for (int i = tid; i < 2 * MAXD + 1; i += 512) bias2s[i] = rel_emb_l[i * H + h] * LOG2E;
    if (tid < 64) colm[0][tid] = (tid > 0 && pad[(size_t)b * S + tid - 1]) ? -1e9f : 0.f;

    // Q fragments (B-frag of QK^T): lane holds Q[qrow][kb8..+7], [+32..]
    const int qrow = q0 + w * 16 + ln15;   // may exceed 1024: in-bounds ws garbage, store-guarded
    bf16x8 qa0 = *(const bf16x8*)(base + (size_t)qrow * 3072 + g4 * 16);
    bf16x8 qa1 = *(const bf16x8*)(base + (size_t)qrow * 3072 + 64 + g4 * 16);

    // V staging: 512 threads x 1 chunk = 64x64 tile. Thread -> V[vr][vd0..+7]
    const int vr = tid >> 3;             // 0..63
    const int vd0 = (tid & 7) * 8;
    const int vsw = ((vd0 >> 3) & 7) << 3;

    { // prologue: stage V tile 0
        bf16x8 a = *(const bf16x8*)(base + (size_t)vr * 3072 + 2048 + vd0 * 2);
#pragma unroll
        for (int j = 0; j < 8; j++)
            Vt[0][(vd0 + j) * PIT + (vr ^ vsw)] = a[j];
    }
    // K fragments tile 0 (A-frag: lane holds K[fj*16+ln15][kb8..+7])
    bf16x8 kr[4][2];
#pragma unroll
    for (int fj = 0; fj < 4; fj++) {
        const char* rp = base + (size_t)(fj * 16 + ln15) * 3072 + 1024 + g4 * 16;
        kr[fj][0] = *(const bf16x8*)(rp);
        kr[fj][1] = *(const bf16x8*)(rp + 64);
    }
    LGKM_BARRIER();

    f32x4 oacc[4] = {};
    float m_prev = -1e30f, l_sum = 0.f;

    for (int t = 0; t < 17; t++) {
        const int k0 = t * 64;
        const int k0n = (k0 + 64 > 1024) ? 1024 : (k0 + 64);
        const int cur = t & 1;

        // A: issue next V load (latency hides under whole tile)
        bf16x8 vA = *(const bf16x8*)(base + (size_t)(k0n + vr) * 3072 + 2048 + vd0 * 2);

        // B: S^T = K @ Q^T : lane holds kv = fj*16 + g4*4 + i, q = ln15
        f32x4 sacc[4] = {};
#pragma unroll
        for (int fj = 0; fj < 4; fj++) {
            sacc[fj] = __builtin_amdgcn_mfma_f32_16x16x32_bf16(kr[fj][0], qa0, sacc[fj], 0, 0, 0);
            sacc[fj] = __builtin_amdgcn_mfma_f32_16x16x32_bf16(kr[fj][1], qa1, sacc[fj], 0, 0, 0);
        }
        // prefetch K for t+1
#pragma unroll
        for (int fj = 0; fj < 4; fj++) {
            const char* rp = base + (size_t)(k0n + fj * 16 + ln15) * 3072 + 1024 + g4 * 16;
            kr[fj][0] = *(const bf16x8*)(rp);
            kr[fj][1] = *(const bf16x8*)(rp + 64);
        }

        // scale + rel-bias + mask (log2 domain)
        float sv[4][4];
        const int relbw = k0 - q0 - w * 16;    // wave-uniform
        if (relbw >= MAXD + 15 || relbw <= -MAXD - 63) {
            const float bu = bias2s[relbw > 0 ? 2 * MAXD : 0];
#pragma unroll
            for (int fj = 0; fj < 4; fj++) {
                f32x4 cm = *(const f32x4*)&colm[cur][fj * 16 + g4 * 4];
#pragma unroll
                for (int i = 0; i < 4; i++)
                    sv[fj][i] = fmaf(sacc[fj][i], C2, bu + cm[i]);
            }
        } else {
            const int relb = k0 - qrow;
#pragma unroll
            for (int fj = 0; fj < 4; fj++) {
                f32x4 cm = *(const f32x4*)&colm[cur][fj * 16 + g4 * 4];
#pragma unroll
                for (int i = 0; i < 4; i++) {
                    int rel = relb + fj * 16 + g4 * 4 + i;
                    rel = rel < -MAXD ? -MAXD : (rel > MAXD ? MAXD : rel);
                    sv[fj][i] = fmaf(sacc[fj][i], C2, bias2s[rel + MAXD] + cm[i]);
                }
            }
        }

        // online softmax: lane-local state for q=ln15; reduce across g4 (lanes ^16, ^32)
        float mx = sv[0][0];
#pragma unroll
        for (int fj = 0; fj < 4; fj++)
#pragma unroll
            for (int i = 0; i < 4; i++) mx = fmaxf(mx, sv[fj][i]);
        mx = fmaxf(mx, __shfl_xor(mx, 16));
        mx = fmaxf(mx, __shfl_xor(mx, 32));
        const float mnew = fmaxf(m_prev, mx);
        const float corr = fexp2(m_prev - mnew);
        float pb[4][4];
        float rsum = 0.f;
#pragma unroll
        for (int fj = 0; fj < 4; fj++)
#pragma unroll
            for (int i = 0; i < 4; i++) {
                float p = fexp2(sv[fj][i] - mnew);
                pb[fj][i] = p;
                rsum += p;
            }
        rsum += __shfl_xor(rsum, 16);
        rsum += __shfl_xor(rsum, 32);
        l_sum = l_sum * corr + rsum;
        m_prev = mnew;
#pragma unroll
        for (int fd = 0; fd < 4; fd++) oacc[fd] *= corr;

        // P -> per-wave LDS: Psh[q=ln15][kv], 8B packed writes
#pragma unroll
        for (int fj = 0; fj < 4; fj++) {
            union { bf16 hh[4]; unsigned long long u; } pk;
            pk.hh[0] = (bf16)pb[fj][0]; pk.hh[1] = (bf16)pb[fj][1];
            pk.hh[2] = (bf16)pb[fj][2]; pk.hh[3] = (bf16)pb[fj][3];
            *(unsigned long long*)&Psh[w][ln15 * PIT + fj * 16 + g4 * 4] = pk.u;
        }

        // W: commit next V tile (swizzled scalar writes) + next colm
#pragma unroll
        for (int j = 0; j < 8; j++)
            Vt[cur ^ 1][(vd0 + j) * PIT + (vr ^ vsw)] = vA[j];
        if (tid < 64) {
            int gk = k0 + 64 + tid;
            int pi = (gk <= 1024) ? gk - 1 : 0;
            colm[cur ^ 1][tid] = (gk > 1024 || pad[(size_t)b * S + pi]) ? -1e9f : 0.f;
        }

        LGKM_BARRIER();   // D1: Vt[cur^1], Psh committed (LDS only; globals in flight)

        // E: O^T += V^T @ P : A-frag = V^T rows (b128 from Vt), B-frag = P (b128 from Psh)
        bf16x8 pa0 = *(const bf16x8*)&Psh[w][ln15 * PIT + kb8];
        bf16x8 pa1 = *(const bf16x8*)&Psh[w][ln15 * PIT + 32 + kb8];
#pragma unroll
        for (int fd = 0; fd < 4; fd++) {
            const int d = fd * 16 + ln15;
            const int vx = ((d >> 3) & 7) << 3;
            bf16x8 af0 = *(const bf16x8*)&Vt[cur][d * PIT + (kb8 ^ vx)];
            bf16x8 af1 = *(const bf16x8*)&Vt[cur][d * PIT + ((32 + kb8) ^ vx)];
            oacc[fd] = __builtin_amdgcn_mfma_f32_16x16x32_bf16(af0, pa0, oacc[fd], 0, 0, 0);
            oacc[fd] = __builtin_amdgcn_mfma_f32_16x16x32_bf16(af1, pa1, oacc[fd], 0, 0, 0);
        }
        LGKM_BARRIER();   // D2: all reads of Vt[cur]/Psh done before overwrite
    }

    // epilogue: lane holds O^T[d = fd*16 + g4*4 + i][q = ln15]; l_sum lane-local
    if (qrow < L) {
        const float inv = 1.f / l_sum;
        bf16* op = ob + (size_t)(b * L + qrow) * D + h * HD + g4 * 4;
#pragma unroll
        for (int fd = 0; fd < 4; fd++) {
            bf16x4 r;
#pragma unroll
            for (int i = 0; i < 4; i++) r[i] = (bf16)(oacc[fd][i] * inv);
            *(bf16x4*)(op + fd * 16) = r;
        }
    }
}

// ---------------- out = LayerNorm(xin + rin), f32 + bf16 copies ----------------
__global__ __launch_bounds__(256) void add_ln_k(const float* __restrict__ xin,
                                                const float* __restrict__ rin,
                                                const float* __restrict__ g,
                                                const float* __restrict__ bb,
                                                float* __restrict__ out,
                                                bf16* __restrict__ outb)
{
    int row = blockIdx.x;
    __shared__ float red[8];
    int tid = threadIdx.x;
    const float* xp = xin + (size_t)row * D;
    const float* rp = rin + (size_t)row * D;
    float v0 = xp[tid] + rp[tid];
    float v1 = xp[tid + 256] + rp[tid + 256];
    float s = v0 + v1;
    for (int off = 32; off; off >>= 1) s += __shfl_down(s, off, 64);
    int lane = tid & 63, wid = tid >> 6;
    if (lane == 0) red[wid] = s;
    __syncthreads();
    if (tid == 0) red[0] = red[0] + red[1] + red[2] + red[3];
    __syncthreads();
    float mean = red[0] * (1.f / D);
    float d0 = v0 - mean, d1 = v1 - mean;
    float sq = d0 * d0 + d1 * d1;
    for (int off = 32; off; off >>= 1) sq += __shfl_down(sq, off, 64);
    if (lane == 0) red[4 + wid] = sq;
    __syncthreads();
    if (tid == 0) red[4] = red[4] + red[5] + red[6] + red[7];
    __syncthreads();
    float rs = rsqrtf(red[4] * (1.f / D) + 1e-5f);
    float r0 = d0 * rs * g[tid] + bb[tid];
    float r1 = d1 * rs * g[tid + 256] + bb[tid + 256];
    out[(size_t)row * D + tid] = r0;
    out[(size_t)row * D + tid + 256] = r1;
    outb[(size_t)row * D + tid] = (bf16)r0;
    outb[(size_t)row * D + tid + 256] = (bf16)r1;
}

// ---------------- final LN (row 0 only) + classifier ----------------
__global__ __launch_bounds__(256) void cls_k(const float* __restrict__ x,
                                             const float* __restrict__ ng,
                                             const float* __restrict__ nb,
                                             const float* __restrict__ cw,
                                             const float* __restrict__ cb,
                                             float* __restrict__ out)
{
    int b = blockIdx.x;
    __shared__ float xn[D];
    __shared__ float red[8];
    int tid = threadIdx.x;
    const float* xp = x + (size_t)(b * L) * D;
    float v0 = xp[tid], v1 = xp[tid + 256];
    float s = v0 + v1;
    for (int off = 32; off; off >>= 1) s += __shfl_down(s, off, 64);
    int lane = tid & 63, wid = tid >> 6;
    if (lane == 0) red[wid] = s;
    __syncthreads();
    if (tid == 0) red[0] = red[0] + red[1] + red[2] + red[3];
    __syncthreads();
    float mean = red[0] * (1.f / D);
    float d0 = v0 - mean, d1 = v1 - mean;
    float sq = d0 * d0 + d1 * d1;
    for (int off = 32; off; off >>= 1) sq += __shfl_down(sq, off, 64);
    if (lane == 0) red[4 + wid] = sq;
    __syncthreads();
    if (tid == 0) red[4] = red[4] + red[5] + red[6] + red[7];
    __syncthreads();
    float rs = rsqrtf(red[4] * (1.f / D) + 1e-5f);
    xn[tid] = d0 * rs * ng[tid] + nb[tid];
    xn[tid + 256] = d1 * rs * ng[tid + 256] + nb[tid + 256];
    __syncthreads();
    for (int o = tid; o < OUTLEN * NC; o += 256) {
        float acc = cb[o];
        const float* wp = cw + (size_t)o * D;
        for (int d = 0; d < D; d++) acc += xn[d] * wp[d];
        out[b * OUTLEN * NC + o] = acc;
    }
}

extern "C" void kernel_launch(void* const* d_in, const int* in_sizes, int n_in,
                              void* d_out, int out_size, void* d_ws, size_t ws_size,
                              hipStream_t stream) {
    const int* src = (const int*)d_in[0];
    const unsigned char* pad = (const unsigned char*)d_in[1];
    const float* emb = (const float*)d_in[2];
    const float* cls_token = (const float*)d_in[3];
    const float* qkv_w = (const float*)d_in[4];
    const float* qkv_b = (const float*)d_in[5];
    const float* out_w = (const float*)d_in[6];
    const float* out_b = (const float*)d_in[7];
    const float* rel_emb = (const float*)d_in[8];
    const float* ln1_g = (const float*)d_in[9];
    const float* ln1_b = (const float*)d_in[10];
    const float* w1 = (const float*)d_in[11];
    const float* b1 = (const float*)d_in[12];
    const float* w2 = (const float*)d_in[13];
    const float* b2 = (const float*)d_in[14];
    const float* ln2_g = (const float*)d_in[15];
    const float* ln2_b = (const float*)d_in[16];
    const float* norm_g = (const float*)d_in[17];
    const float* norm_b = (const float*)d_in[18];
    const float* cls_w = (const float*)d_in[19];
    const float* cls_b = (const float*)d_in[20];
    float* out = (float*)d_out;

    char* ws = (char*)d_ws;
    size_t off = 0;
    float* x   = (float*)(ws + off); off += (size_t)MP * D * 4;
    bf16*  xb  = (bf16*) (ws + off); off += (size_t)MP * D * 2;
    float* x2  = (float*)(ws + off); off += (size_t)MP * D * 4;
    bf16*  x2b = (bf16*) (ws + off); off += (size_t)MP * D * 2;
    char*  R   = ws + off;           off += (size_t)MP * 3 * D * 4; // qkvb | (hb + p)
    bf16*  qkvb = (bf16*)R;                              // MP*3D*2
    bf16*  hb  = (bf16*)R;                               // MP*FF*2 (after attn)
    float* p   = (float*)(R + (size_t)MP * FF * 2);      // MP*D*4
    bf16*  obf = (bf16*) (ws + off); off += (size_t)MP * D * 2;

    const size_t WQ = (size_t)NL * 3 * D * D;
    const size_t WO = (size_t)NL * D * D;
    const size_t W1E = (size_t)NL * FF * D;
    const size_t W2E = (size_t)NL * D * FF;
    const size_t WALL = WQ + WO + W1E + W2E;
    bool all_w = (off + WALL * 2) <= ws_size;

    bf16 *wq_a = nullptr, *wo_a = nullptr, *w1_a = nullptr, *w2_a = nullptr, *wbuf = nullptr;
    if (all_w) {
        wq_a = (bf16*)(ws + off);
        wo_a = wq_a + WQ;
        w1_a = wo_a + WO;
        w2_a = w1_a + W1E;
        int n4;
        n4 = (int)(WQ / 4);  cvt_k<<<dim3((n4 + 255) / 256), 256, 0, stream>>>(qkv_w, wq_a, n4);
        n4 = (int)(WO / 4);  cvt_k<<<dim3((n4 + 255) / 256), 256, 0, stream>>>(out_w, wo_a, n4);
        n4 = (int)(W1E / 4); cvt_k<<<dim3((n4 + 255) / 256), 256, 0, stream>>>(w1, w1_a, n4);
        n4 = (int)(W2E / 4); cvt_k<<<dim3((n4 + 255) / 256), 256, 0, stream>>>(w2, w2_a, n4);
    } else {
        wbuf = (bf16*)(ws + off); // per-layer rotating buffer
    }

    const int M = B * L;
    {
        long total = (long)B * L * D;
        embed_k<<<dim3((unsigned)((total + 255) / 256)), 256, 0, stream>>>(src, emb, cls_token, x, xb);
    }
    for (int l = 0; l < NL; l++) {
        const float* qb  = qkv_b + (size_t)l * 3 * D;
        const float* obi = out_b + (size_t)l * D;
        const float* re  = rel_emb + (size_t)l * (2 * MAXD + 1) * H;
        const float* g1  = ln1_g + (size_t)l * D;
        const float* be1 = ln1_b + (size_t)l * D;
        const float* B1p = b1 + (size_t)l * FF;
        const float* B2p = b2 + (size_t)l * D;
        const float* g2  = ln2_g + (size_t)l * D;
        const float* be2 = ln2_b + (size_t)l * D;

        const bf16 *wqb, *wob, *w1b, *w2b;
        if (all_w) {
            wqb = wq_a + (size_t)l * 3 * D * D;
            wob = wo_a + (size_t)l * D * D;
            w1b = w1_a + (size_t)l * FF * D;
            w2b = w2_a + (size_t)l * D * FF;
        } else {
            bf16* wp_ = wbuf;
            wqb = wp_;            wp_ += 3 * D * D;
            wob = wp_;            wp_ += D * D;
            w1b = wp_;            wp_ += FF * D;
            w2b = wp_;
            int n4;
            n4 = 3 * D * D / 4; cvt_k<<<dim3((n4 + 255) / 256), 256, 0, stream>>>(qkv_w + (size_t)l * 3 * D * D, (bf16*)wqb, n4);
            n4 = D * D / 4;     cvt_k<<<dim3((n4 + 255) / 256), 256, 0, stream>>>(out_w + (size_t)l * D * D, (bf16*)wob, n4);
            n4 = FF * D / 4;    cvt_k<<<dim3((n4 + 255) / 256), 256, 0, stream>>>(w1 + (size_t)l * FF * D, (bf16*)w1b, n4);
            n4 = D * FF / 4;    cvt_k<<<dim3((n4 + 255) / 256), 256, 0, stream>>>(w2 + (size_t)l * D * FF, (bf16*)w2b, n4);
        }

        mgemm<0, 1><<<dim3(3 * D / 128, MP / 128), 256, 0, stream>>>(xb, wqb, qb, nullptr, qkvb, 3 * D, D);
        fattn_k<<<dim3(B * H, (L + 127) / 128), 512, 0, stream>>>(qkvb, re, pad, obf);
        mgemm<0, 0><<<dim3(D / 128, MP / 128), 256, 0, stream>>>(obf, wob, obi, p, nullptr, D, D);
        add_ln_k<<<dim3(M), 256, 0, stream>>>(x, p, g1, be1, x2, x2b);
        mgemm<1, 1><<<dim3(FF / 128, MP / 128), 256, 0, stream>>>(x2b, w1b, B1p, nullptr, hb, FF, D);
        mgemm<0, 0><<<dim3(D / 128, MP / 128), 256, 0, stream>>>(hb, w2b, B2p, p, nullptr, D, FF);
        add_ln_k<<<dim3(M), 256, 0, stream>>>(x2, p, g2, be2, x, xb);
    }
    cls_k<<<dim3(B), 256, 0, stream>>>(x, norm_g, norm_b, cls_w, cls_b, out);
}

// Round 12
// 1634.068 us; speedup vs baseline: 1.0939x; 1.0907x over previous
//
#include <hip/hip_runtime.h>
#include <hip/hip_bf16.h>
#include <stdint.h>

#define B 8
#define S 1024
#define L 1025
#define D 512
#define H 8
#define HD 64
#define NL 6
#define FF 2048
#define MAXD 64
#define OUTLEN 8
#define NC 10

#define MP 8320   // 65 * 128, padded M

typedef __bf16 bf16;
typedef __bf16 bf16x8 __attribute__((ext_vector_type(8)));
typedef __bf16 bf16x4 __attribute__((ext_vector_type(4)));
typedef float f32x4 __attribute__((ext_vector_type(4)));

__device__ __forceinline__ float fexp2(float x) { return __builtin_amdgcn_exp2f(x); }

// barrier WITHOUT the vmcnt(0) drain
#define LGKM_BARRIER() asm volatile("s_waitcnt lgkmcnt(0)\ns_barrier" ::: "memory")

__device__ __forceinline__ void gld16(const void* g, void* l) {
    __builtin_amdgcn_global_load_lds(
        (const __attribute__((address_space(1))) unsigned int*)g,
        (__attribute__((address_space(3))) unsigned int*)l,
        16, 0, 0);
}

// GELU with A&S 7.1.26 erf (|err| <= 1.5e-7), no libm call
__device__ __forceinline__ float fast_gelu(float v) {
    float x = v * 0.70710678118654752f;
    float ax = fabsf(x);
    float t = 1.f / fmaf(0.3275911f, ax, 1.f);
    float poly = t * (0.254829592f + t * (-0.284496736f + t * (1.421413741f +
                 t * (-1.453152027f + t * 1.061405429f))));
    float e = fexp2(-ax * ax * 1.4426950408889634f);
    float erfv = 1.f - poly * e;
    erfv = copysignf(erfv, x);
    return 0.5f * v * (1.f + erfv);
}

// ---------------- f32 -> bf16 conversion (vectorized) ----------------
__global__ __launch_bounds__(256) void cvt_k(const float* __restrict__ in,
                                             bf16* __restrict__ out, int n4)
{
    int i = blockIdx.x * 256 + threadIdx.x;
    if (i >= n4) return;
    float4 v = reinterpret_cast<const float4*>(in)[i];
    bf16x4 o;
    o[0] = (bf16)v.x; o[1] = (bf16)v.y; o[2] = (bf16)v.z; o[3] = (bf16)v.w;
    reinterpret_cast<bf16x4*>(out)[i] = o;
}

// ---------------- embedding ----------------
__global__ void embed_k(const int* __restrict__ src, const float* __restrict__ emb,
                        const float* __restrict__ cls, float* __restrict__ x,
                        bf16* __restrict__ xb)
{
    long i = (long)blockIdx.x * blockDim.x + threadIdx.x;
    if (i >= (long)B * L * D) return;
    int d = (int)(i % D);
    long bl = i / D;
    int l = (int)(bl % L);
    int b = (int)(bl / L);
    float v = (l == 0) ? cls[d] : emb[(long)src[b * S + (l - 1)] * D + d];
    x[i] = v;
    xb[i] = (bf16)v;
}

// ---------------- MFMA bf16 GEMM: C[MP,N] = A[MP,Kpart] @ W[N,Kpart]^T (+bias) ----
// LDA = row stride of A and W (== full K; Kpart may be a K-slice for split-K)
template<int ACT, int OBF, int BIAS>
__global__ __launch_bounds__(256) void mgemm(const bf16* __restrict__ A,
                                             const bf16* __restrict__ W,
                                             const float* __restrict__ bias,
                                             float* __restrict__ Cf,
                                             bf16* __restrict__ Cb,
                                             int N, int K, int LDA)
{
    __shared__ bf16 Asl[128 * 32];
    __shared__ bf16 Bsl[128 * 32];
    int tid = threadIdx.x;
    int m0 = blockIdx.y * 128;
    int n0 = blockIdx.x * 128;
    int lane = tid & 63;
    int w = tid >> 6, wr = w >> 1, wc = w & 1;
    int wbase = tid & ~63;
    int kb = (lane >> 4) * 8;
    int rsel = lane & 15;
    f32x4 acc[4][4] = {};

    for (int k0 = 0; k0 < K; k0 += 32) {
#pragma unroll
        for (int r = 0; r < 2; r++) {
            int s = r * 256 + tid;
            int sb = r * 256 + wbase;
            gld16(A + (size_t)(m0 + (s >> 2)) * LDA + k0 + (s & 3) * 8, &Asl[(size_t)sb * 8]);
            gld16(W + (size_t)(n0 + (s >> 2)) * LDA + k0 + (s & 3) * 8, &Bsl[(size_t)sb * 8]);
        }
        __syncthreads();
        bf16x8 af[4], bfr[4];
#pragma unroll
        for (int fi = 0; fi < 4; fi++)
            af[fi] = *reinterpret_cast<const bf16x8*>(&Asl[(wr * 64 + fi * 16 + rsel) * 32 + kb]);
#pragma unroll
        for (int fj = 0; fj < 4; fj++)
            bfr[fj] = *reinterpret_cast<const bf16x8*>(&Bsl[(wc * 64 + fj * 16 + rsel) * 32 + kb]);
#pragma unroll
        for (int fi = 0; fi < 4; fi++)
#pragma unroll
            for (int fj = 0; fj < 4; fj++)
                acc[fi][fj] = __builtin_amdgcn_mfma_f32_16x16x32_bf16(af[fi], bfr[fj], acc[fi][fj], 0, 0, 0);
        __syncthreads();
    }
    int rowb = (lane >> 4) * 4;
    int colb = lane & 15;
#pragma unroll
    for (int fi = 0; fi < 4; fi++) {
#pragma unroll
        for (int fj = 0; fj < 4; fj++) {
            int col = n0 + wc * 64 + fj * 16 + colb;
            float bsv = BIAS ? bias[col] : 0.f;
#pragma unroll
            for (int i = 0; i < 4; i++) {
                int row = m0 + wr * 64 + fi * 16 + rowb + i;
                float v = acc[fi][fj][i] + bsv;
                if (ACT) v = fast_gelu(v);
                if (OBF) Cb[(size_t)row * N + col] = (bf16)v;
                else     Cf[(size_t)row * N + col] = v;
            }
        }
    }
}

// ---------------- MFMA flash attention v7: 2 q-tiles share K/V pipeline -------
// R9-verified per-wave structure; each block processes q-rows [q0, q0+128).
// K frags, V staging, colm, barriers are per-KV-tile costs shared by both
// q-subtiles -> 2x MFMA per tile amortizes the fixed per-tile latency.
__global__ __launch_bounds__(256) void fattn_k(const bf16* __restrict__ qkv,
                                               const float* __restrict__ rel_emb_l,
                                               const unsigned char* __restrict__ pad,
                                               bf16* __restrict__ ob)
{
    constexpr int PIT = 72;
    __shared__ bf16 Vt[2][64 * PIT];       // V^T[d][k ^ ((d>>3)<<3)]
    __shared__ bf16 Psh[4][2][16 * PIT];   // per-wave, per-qq P[q][kv]
    __shared__ float bias2s[2 * MAXD + 1];
    __shared__ float colm[2][64];

    const int bh = blockIdx.x;
    const int qt = blockIdx.y;
    const int h = bh & 7, b = bh >> 3;
    const int q0 = qt * 128;
    const int tid = threadIdx.x;
    const int lane = tid & 63;
    const int w = tid >> 6;
    const int ln15 = lane & 15, g4 = lane >> 4;
    const int kb8 = g4 * 8;
    constexpr float LOG2E = 1.4426950408889634f;
    constexpr float C2 = 0.125f * LOG2E;

    const char* base = (const char*)qkv + (size_t)(b * L) * 3072 + (size_t)h * (HD * 2);

    for (int i = tid; i < 2 * MAXD + 1; i += 256) bias2s[i] = rel_emb_l[i * H + h] * LOG2E;
    if (tid < 64) colm[0][tid] = (tid > 0 && pad[(size_t)b * S + tid - 1]) ? -1e9f : 0.f;

    // Q fragments for both q-subtiles (rows may exceed L: in-ws garbage, store-guarded)
    int qrow[2];
    bf16x8 qa[2][2];
#pragma unroll
    for (int qq = 0; qq < 2; qq++) {
        qrow[qq] = q0 + qq * 64 + w * 16 + ln15;
        qa[qq][0] = *(const bf16x8*)(base + (size_t)qrow[qq] * 3072 + g4 * 16);
        qa[qq][1] = *(const bf16x8*)(base + (size_t)qrow[qq] * 3072 + 64 + g4 * 16);
    }

    // V staging mapping (as R9): thread loads V[vr][vd0..+7], V[vr+32][vd0..+7]
    const int vr = tid >> 3;
    const int vd0 = (tid & 7) * 8;
    const int vsw = ((vd0 >> 3) & 7) << 3;

    { // prologue: stage V tile 0
        bf16x8 a = *(const bf16x8*)(base + (size_t)vr * 3072 + 2048 + vd0 * 2);
        bf16x8 c = *(const bf16x8*)(base + (size_t)(vr + 32) * 3072 + 2048 + vd0 * 2);
#pragma unroll
        for (int j = 0; j < 8; j++) {
            Vt[0][(vd0 + j) * PIT + (vr ^ vsw)] = a[j];
            Vt[0][(vd0 + j) * PIT + ((vr + 32) ^ vsw)] = c[j];
        }
    }
    // K fragments tile 0
    bf16x8 kr[4][2];
#pragma unroll
    for (int fj = 0; fj < 4; fj++) {
        const char* rp = base + (size_t)(fj * 16 + ln15) * 3072 + 1024 + g4 * 16;
        kr[fj][0] = *(const bf16x8*)(rp);
        kr[fj][1] = *(const bf16x8*)(rp + 64);
    }
    LGKM_BARRIER();

    f32x4 oacc[2][4] = {};
    float m_prev[2] = {-1e30f, -1e30f};
    float l_sum[2] = {0.f, 0.f};

    for (int t = 0; t < 17; t++) {
        const int k0 = t * 64;
        const int k0n = (k0 + 64 > 1024) ? 1024 : (k0 + 64);
        const int cur = t & 1;

        // issue next V loads
        bf16x8 vA = *(const bf16x8*)(base + (size_t)(k0n + vr) * 3072 + 2048 + vd0 * 2);
        bf16x8 vB = *(const bf16x8*)(base + (size_t)(k0n + vr + 32) * 3072 + 2048 + vd0 * 2);

        // QK^T for both q-subtiles (kr shared)
        f32x4 sacc[2][4] = {};
#pragma unroll
        for (int qq = 0; qq < 2; qq++)
#pragma unroll
            for (int fj = 0; fj < 4; fj++) {
                sacc[qq][fj] = __builtin_amdgcn_mfma_f32_16x16x32_bf16(kr[fj][0], qa[qq][0], sacc[qq][fj], 0, 0, 0);
                sacc[qq][fj] = __builtin_amdgcn_mfma_f32_16x16x32_bf16(kr[fj][1], qa[qq][1], sacc[qq][fj], 0, 0, 0);
            }
        // prefetch K for t+1
#pragma unroll
        for (int fj = 0; fj < 4; fj++) {
            const char* rp = base + (size_t)(k0n + fj * 16 + ln15) * 3072 + 1024 + g4 * 16;
            kr[fj][0] = *(const bf16x8*)(rp);
            kr[fj][1] = *(const bf16x8*)(rp + 64);
        }

        // shared mask row
        f32x4 cm[4];
#pragma unroll
        for (int fj = 0; fj < 4; fj++)
            cm[fj] = *(const f32x4*)&colm[cur][fj * 16 + g4 * 4];

        // per-subtile: bias/mask + online softmax + P write
#pragma unroll
        for (int qq = 0; qq < 2; qq++) {
            float sv[4][4];
            const int relbw = k0 - q0 - qq * 64 - w * 16;
            if (relbw >= MAXD + 15 || relbw <= -MAXD - 63) {
                const float bu = bias2s[relbw > 0 ? 2 * MAXD : 0];
#pragma unroll
                for (int fj = 0; fj < 4; fj++)
#pragma unroll
                    for (int i = 0; i < 4; i++)
                        sv[fj][i] = fmaf(sacc[qq][fj][i], C2, bu + cm[fj][i]);
            } else {
                const int relb = k0 - qrow[qq];
#pragma unroll
                for (int fj = 0; fj < 4; fj++)
#pragma unroll
                    for (int i = 0; i < 4; i++) {
                        int rel = relb + fj * 16 + g4 * 4 + i;
                        rel = rel < -MAXD ? -MAXD : (rel > MAXD ? MAXD : rel);
                        sv[fj][i] = fmaf(sacc[qq][fj][i], C2, bias2s[rel + MAXD] + cm[fj][i]);
                    }
            }

            float mx = sv[0][0];
#pragma unroll
            for (int fj = 0; fj < 4; fj++)
#pragma unroll
                for (int i = 0; i < 4; i++) mx = fmaxf(mx, sv[fj][i]);
            mx = fmaxf(mx, __shfl_xor(mx, 16));
            mx = fmaxf(mx, __shfl_xor(mx, 32));
            const float mnew = fmaxf(m_prev[qq], mx);
            const float corr = fexp2(m_prev[qq] - mnew);
            float rsum = 0.f;
            float pb[4][4];
#pragma unroll
            for (int fj = 0; fj < 4; fj++)
#pragma unroll
                for (int i = 0; i < 4; i++) {
                    float p = fexp2(sv[fj][i] - mnew);
                    pb[fj][i] = p;
                    rsum += p;
                }
            rsum += __shfl_xor(rsum, 16);
            rsum += __shfl_xor(rsum, 32);
            l_sum[qq] = l_sum[qq] * corr + rsum;
            m_prev[qq] = mnew;
#pragma unroll
            for (int fd = 0; fd < 4; fd++) oacc[qq][fd] *= corr;

#pragma unroll
            for (int fj = 0; fj < 4; fj++) {
                union { bf16 hh[4]; unsigned long long u; } pk;
                pk.hh[0] = (bf16)pb[fj][0]; pk.hh[1] = (bf16)pb[fj][1];
                pk.hh[2] = (bf16)pb[fj][2]; pk.hh[3] = (bf16)pb[fj][3];
                *(unsigned long long*)&Psh[w][qq][ln15 * PIT + fj * 16 + g4 * 4] = pk.u;
            }
        }

        // commit next V tile + next colm
#pragma unroll
        for (int j = 0; j < 8; j++) {
            Vt[cur ^ 1][(vd0 + j) * PIT + (vr ^ vsw)] = vA[j];
            Vt[cur ^ 1][(vd0 + j) * PIT + ((vr + 32) ^ vsw)] = vB[j];
        }
        if (tid < 64) {
            int gk = k0 + 64 + tid;
            int pi = (gk <= 1024) ? gk - 1 : 0;
            colm[cur ^ 1][tid] = (gk > 1024 || pad[(size_t)b * S + pi]) ? -1e9f : 0.f;
        }

        LGKM_BARRIER();   // D1: Vt[cur^1] + Psh committed

        // PV: V fragments loaded once, used for both q-subtiles
        bf16x8 pa[2][2];
#pragma unroll
        for (int qq = 0; qq < 2; qq++) {
            pa[qq][0] = *(const bf16x8*)&Psh[w][qq][ln15 * PIT + kb8];
            pa[qq][1] = *(const bf16x8*)&Psh[w][qq][ln15 * PIT + 32 + kb8];
        }
#pragma unroll
        for (int fd = 0; fd < 4; fd++) {
            const int d = fd * 16 + ln15;
            const int vx = ((d >> 3) & 7) << 3;
            bf16x8 af0 = *(const bf16x8*)&Vt[cur][d * PIT + (kb8 ^ vx)];
            bf16x8 af1 = *(const bf16x8*)&Vt[cur][d * PIT + ((32 + kb8) ^ vx)];
            oacc[0][fd] = __builtin_amdgcn_mfma_f32_16x16x32_bf16(af0, pa[0][0], oacc[0][fd], 0, 0, 0);
            oacc[0][fd] = __builtin_amdgcn_mfma_f32_16x16x32_bf16(af1, pa[0][1], oacc[0][fd], 0, 0, 0);
            oacc[1][fd] = __builtin_amdgcn_mfma_f32_16x16x32_bf16(af0, pa[1][0], oacc[1][fd], 0, 0, 0);
            oacc[1][fd] = __builtin_amdgcn_mfma_f32_16x16x32_bf16(af1, pa[1][1], oacc[1][fd], 0, 0, 0);
        }
        LGKM_BARRIER();   // D2: Vt[cur]/Psh reads done before overwrite
    }

    // epilogue
#pragma unroll
    for (int qq = 0; qq < 2; qq++) {
        if (qrow[qq] < L) {
            const float inv = 1.f / l_sum[qq];
            bf16* op = ob + (size_t)(b * L + qrow[qq]) * D + h * HD + g4 * 4;
#pragma unroll
            for (int fd = 0; fd < 4; fd++) {
                bf16x4 r;
#pragma unroll
                for (int i = 0; i < 4; i++) r[i] = (bf16)(oacc[qq][fd][i] * inv);
                *(bf16x4*)(op + fd * 16) = r;
            }
        }
    }
}

// ---------------- out = LayerNorm(xin + rin), f32 + bf16 copies ----------------
__global__ __launch_bounds__(256) void add_ln_k(const float* __restrict__ xin,
                                                const float* __restrict__ rin,
                                                const float* __restrict__ g,
                                                const float* __restrict__ bb,
                                                float* __restrict__ out,
                                                bf16* __restrict__ outb)
{
    int row = blockIdx.x;
    __shared__ float red[8];
    int tid = threadIdx.x;
    const float* xp = xin + (size_t)row * D;
    const float* rp = rin + (size_t)row * D;
    float v0 = xp[tid] + rp[tid];
    float v1 = xp[tid + 256] + rp[tid + 256];
    float s = v0 + v1;
    for (int off = 32; off; off >>= 1) s += __shfl_down(s, off, 64);
    int lane = tid & 63, wid = tid >> 6;
    if (lane == 0) red[wid] = s;
    __syncthreads();
    if (tid == 0) red[0] = red[0] + red[1] + red[2] + red[3];
    __syncthreads();
    float mean = red[0] * (1.f / D);
    float d0 = v0 - mean, d1 = v1 - mean;
    float sq = d0 * d0 + d1 * d1;
    for (int off = 32; off; off >>= 1) sq += __shfl_down(sq, off, 64);
    if (lane == 0) red[4 + wid] = sq;
    __syncthreads();
    if (tid == 0) red[4] = red[4] + red[5] + red[6] + red[7];
    __syncthreads();
    float rs = rsqrtf(red[4] * (1.f / D) + 1e-5f);
    float r0 = d0 * rs * g[tid] + bb[tid];
    float r1 = d1 * rs * g[tid + 256] + bb[tid + 256];
    out[(size_t)row * D + tid] = r0;
    out[(size_t)row * D + tid + 256] = r1;
    outb[(size_t)row * D + tid] = (bf16)r0;
    outb[(size_t)row * D + tid + 256] = (bf16)r1;
}

// ---------------- out = LayerNorm(xin + r0 + r1b) (split-K FF2 epilogue) -------
__global__ __launch_bounds__(256) void add_ln3_k(const float* __restrict__ xin,
                                                 const float* __restrict__ r0in,
                                                 const bf16* __restrict__ r1in,
                                                 const float* __restrict__ g,
                                                 const float* __restrict__ bb,
                                                 float* __restrict__ out,
                                                 bf16* __restrict__ outb)
{
    int row = blockIdx.x;
    __shared__ float red[8];
    int tid = threadIdx.x;
    const float* xp = xin + (size_t)row * D;
    const float* rp = r0in + (size_t)row * D;
    const bf16* r1p = r1in + (size_t)row * D;
    float v0 = xp[tid] + rp[tid] + (float)r1p[tid];
    float v1 = xp[tid + 256] + rp[tid + 256] + (float)r1p[tid + 256];
    float s = v0 + v1;
    for (int off = 32; off; off >>= 1) s += __shfl_down(s, off, 64);
    int lane = tid & 63, wid = tid >> 6;
    if (lane == 0) red[wid] = s;
    __syncthreads();
    if (tid == 0) red[0] = red[0] + red[1] + red[2] + red[3];
    __syncthreads();
    float mean = red[0] * (1.f / D);
    float d0 = v0 - mean, d1 = v1 - mean;
    float sq = d0 * d0 + d1 * d1;
    for (int off = 32; off; off >>= 1) sq += __shfl_down(sq, off, 64);
    if (lane == 0) red[4 + wid] = sq;
    __syncthreads();
    if (tid == 0) red[4] = red[4] + red[5] + red[6] + red[7];
    __syncthreads();
    float rs = rsqrtf(red[4] * (1.f / D) + 1e-5f);
    float r0 = d0 * rs * g[tid] + bb[tid];
    float r1 = d1 * rs * g[tid + 256] + bb[tid + 256];
    out[(size_t)row * D + tid] = r0;
    out[(size_t)row * D + tid + 256] = r1;
    outb[(size_t)row * D + tid] = (bf16)r0;
    outb[(size_t)row * D + tid + 256] = (bf16)r1;
}

// ---------------- final LN (row 0 only) + classifier ----------------
__global__ __launch_bounds__(256) void cls_k(const float* __restrict__ x,
                                             const float* __restrict__ ng,
                                             const float* __restrict__ nb,
                                             const float* __restrict__ cw,
                                             const float* __restrict__ cb,
                                             float* __restrict__ out)
{
    int b = blockIdx.x;
    __shared__ float xn[D];
    __shared__ float red[8];
    int tid = threadIdx.x;
    const float* xp = x + (size_t)(b * L) * D;
    float v0 = xp[tid], v1 = xp[tid + 256];
    float s = v0 + v1;
    for (int off = 32; off; off >>= 1) s += __shfl_down(s, off, 64);
    int lane = tid & 63, wid = tid >> 6;
    if (lane == 0) red[wid] = s;
    __syncthreads();
    if (tid == 0) red[0] = red[0] + red[1] + red[2] + red[3];
    __syncthreads();
    float mean = red[0] * (1.f / D);
    float d0 = v0 - mean, d1 = v1 - mean;
    float sq = d0 * d0 + d1 * d1;
    for (int off = 32; off; off >>= 1) sq += __shfl_down(sq, off, 64);
    if (lane == 0) red[4 + wid] = sq;
    __syncthreads();
    if (tid == 0) red[4] = red[4] + red[5] + red[6] + red[7];
    __syncthreads();
    float rs = rsqrtf(red[4] * (1.f / D) + 1e-5f);
    xn[tid] = d0 * rs * ng[tid] + nb[tid];
    xn[tid + 256] = d1 * rs * ng[tid + 256] + nb[tid + 256];
    __syncthreads();
    for (int o = tid; o < OUTLEN * NC; o += 256) {
        float acc = cb[o];
        const float* wp = cw + (size_t)o * D;
        for (int d = 0; d < D; d++) acc += xn[d] * wp[d];
        out[b * OUTLEN * NC + o] = acc;
    }
}

extern "C" void kernel_launch(void* const* d_in, const int* in_sizes, int n_in,
                              void* d_out, int out_size, void* d_ws, size_t ws_size,
                              hipStream_t stream) {
    const int* src = (const int*)d_in[0];
    const unsigned char* pad = (const unsigned char*)d_in[1];
    const float* emb = (const float*)d_in[2];
    const float* cls_token = (const float*)d_in[3];
    const float* qkv_w = (const float*)d_in[4];
    const float* qkv_b = (const float*)d_in[5];
    const float* out_w = (const float*)d_in[6];
    const float* out_b = (const float*)d_in[7];
    const float* rel_emb = (const float*)d_in[8];
    const float* ln1_g = (const float*)d_in[9];
    const float* ln1_b = (const float*)d_in[10];
    const float* w1 = (const float*)d_in[11];
    const float* b1 = (const float*)d_in[12];
    const float* w2 = (const float*)d_in[13];
    const float* b2 = (const float*)d_in[14];
    const float* ln2_g = (const float*)d_in[15];
    const float* ln2_b = (const float*)d_in[16];
    const float* norm_g = (const float*)d_in[17];
    const float* norm_b = (const float*)d_in[18];
    const float* cls_w = (const float*)d_in[19];
    const float* cls_b = (const float*)d_in[20];
    float* out = (float*)d_out;

    char* ws = (char*)d_ws;
    size_t off = 0;
    float* x   = (float*)(ws + off); off += (size_t)MP * D * 4;
    bf16*  xb  = (bf16*) (ws + off); off += (size_t)MP * D * 2;
    float* x2  = (float*)(ws + off); off += (size_t)MP * D * 4;
    bf16*  x2b = (bf16*) (ws + off); off += (size_t)MP * D * 2;
    char*  R   = ws + off;           off += (size_t)MP * 3 * D * 4; // qkvb | (hb + p)
    bf16*  qkvb = (bf16*)R;                              // MP*3D*2
    bf16*  hb  = (bf16*)R;                               // MP*FF*2 (after attn)
    float* p   = (float*)(R + (size_t)MP * FF * 2);      // MP*D*4
    bf16*  obf = (bf16*) (ws + off); off += (size_t)MP * D * 2;

    const size_t WQ = (size_t)NL * 3 * D * D;
    const size_t WO = (size_t)NL * D * D;
    const size_t W1E = (size_t)NL * FF * D;
    const size_t W2E = (size_t)NL * D * FF;
    const size_t WALL = WQ + WO + W1E + W2E;
    bool all_w = (off + WALL * 2) <= ws_size;

    bf16 *wq_a = nullptr, *wo_a = nullptr, *w1_a = nullptr, *w2_a = nullptr, *wbuf = nullptr;
    if (all_w) {
        wq_a = (bf16*)(ws + off);
        wo_a = wq_a + WQ;
        w1_a = wo_a + WO;
        w2_a = w1_a + W1E;
        int n4;
        n4 = (int)(WQ / 4);  cvt_k<<<dim3((n4 + 255) / 256), 256, 0, stream>>>(qkv_w, wq_a, n4);
        n4 = (int)(WO / 4);  cvt_k<<<dim3((n4 + 255) / 256), 256, 0, stream>>>(out_w, wo_a, n4);
        n4 = (int)(W1E / 4); cvt_k<<<dim3((n4 + 255) / 256), 256, 0, stream>>>(w1, w1_a, n4);
        n4 = (int)(W2E / 4); cvt_k<<<dim3((n4 + 255) / 256), 256, 0, stream>>>(w2, w2_a, n4);
    } else {
        wbuf = (bf16*)(ws + off); // per-layer rotating buffer
    }

    const int M = B * L;
    {
        long total = (long)B * L * D;
        embed_k<<<dim3((unsigned)((total + 255) / 256)), 256, 0, stream>>>(src, emb, cls_token, x, xb);
    }
    for (int l = 0; l < NL; l++) {
        const float* qb  = qkv_b + (size_t)l * 3 * D;
        const float* obi = out_b + (size_t)l * D;
        const float* re  = rel_emb + (size_t)l * (2 * MAXD + 1) * H;
        const float* g1  = ln1_g + (size_t)l * D;
        const float* be1 = ln1_b + (size_t)l * D;
        const float* B1p = b1 + (size_t)l * FF;
        const float* B2p = b2 + (size_t)l * D;
        const float* g2  = ln2_g + (size_t)l * D;
        const float* be2 = ln2_b + (size_t)l * D;

        const bf16 *wqb, *wob, *w1b, *w2b;
        if (all_w) {
            wqb = wq_a + (size_t)l * 3 * D * D;
            wob = wo_a + (size_t)l * D * D;
            w1b = w1_a + (size_t)l * FF * D;
            w2b = w2_a + (size_t)l * D * FF;
        } else {
            bf16* wp_ = wbuf;
            wqb = wp_;            wp_ += 3 * D * D;
            wob = wp_;            wp_ += D * D;
            w1b = wp_;            wp_ += FF * D;
            w2b = wp_;
            int n4;
            n4 = 3 * D * D / 4; cvt_k<<<dim3((n4 + 255) / 256), 256, 0, stream>>>(qkv_w + (size_t)l * 3 * D * D, (bf16*)wqb, n4);
            n4 = D * D / 4;     cvt_k<<<dim3((n4 + 255) / 256), 256, 0, stream>>>(out_w + (size_t)l * D * D, (bf16*)wob, n4);
            n4 = FF * D / 4;    cvt_k<<<dim3((n4 + 255) / 256), 256, 0, stream>>>(w1 + (size_t)l * FF * D, (bf16*)w1b, n4);
            n4 = D * FF / 4;    cvt_k<<<dim3((n4 + 255) / 256), 256, 0, stream>>>(w2 + (size_t)l * D * FF, (bf16*)w2b, n4);
        }

        mgemm<0, 1, 1><<<dim3(3 * D / 128, MP / 128), 256, 0, stream>>>(xb, wqb, qb, nullptr, qkvb, 3 * D, D, D);
        fattn_k<<<dim3(B * H, 9), 256, 0, stream>>>(qkvb, re, pad, obf);
        mgemm<0, 0, 1><<<dim3(D / 128, MP / 128), 256, 0, stream>>>(obf, wob, obi, p, nullptr, D, D, D);
        add_ln_k<<<dim3(M), 256, 0, stream>>>(x, p, g1, be1, x2, x2b);
        mgemm<1, 1, 1><<<dim3(FF / 128, MP / 128), 256, 0, stream>>>(x2b, w1b, B1p, nullptr, hb, FF, D, D);
        // FF2 split-K: first half (with bias) -> p (f32); second half -> xb (bf16 partial, xb is dead here)
        mgemm<0, 0, 1><<<dim3(D / 128, MP / 128), 256, 0, stream>>>(hb, w2b, B2p, p, nullptr, D, FF / 2, FF);
        mgemm<0, 1, 0><<<dim3(D / 128, MP / 128), 256, 0, stream>>>(hb + FF / 2, w2b + FF / 2, B2p, nullptr, xb, D, FF / 2, FF);
        add_ln3_k<<<dim3(M), 256, 0, stream>>>(x2, p, xb, g2, be2, x, xb);
    }
    cls_k<<<dim3(B), 256, 0, stream>>>(x, norm_g, norm_b, cls_w, cls_b, out);
}

// Round 13
// 1557.874 us; speedup vs baseline: 1.1474x; 1.0489x over previous
//
#include <hip/hip_runtime.h>
#include <hip/hip_bf16.h>
#include <stdint.h>

#define B 8
#define S 1024
#define L 1025
#define D 512
#define H 8
#define HD 64
#define NL 6
#define FF 2048
#define MAXD 64
#define OUTLEN 8
#define NC 10

#define MP 8320   // 65 * 128, padded M

typedef __bf16 bf16;
typedef __bf16 bf16x8 __attribute__((ext_vector_type(8)));
typedef __bf16 bf16x4 __attribute__((ext_vector_type(4)));
typedef float f32x4 __attribute__((ext_vector_type(4)));

__device__ __forceinline__ float fexp2(float x) { return __builtin_amdgcn_exp2f(x); }

// barrier WITHOUT the vmcnt(0) drain
#define LGKM_BARRIER() asm volatile("s_waitcnt lgkmcnt(0)\ns_barrier" ::: "memory")

__device__ __forceinline__ void gld16(const void* g, void* l) {
    __builtin_amdgcn_global_load_lds(
        (const __attribute__((address_space(1))) unsigned int*)g,
        (__attribute__((address_space(3))) unsigned int*)l,
        16, 0, 0);
}

// GELU with A&S 7.1.26 erf (|err| <= 1.5e-7), no libm call
__device__ __forceinline__ float fast_gelu(float v) {
    float x = v * 0.70710678118654752f;
    float ax = fabsf(x);
    float t = 1.f / fmaf(0.3275911f, ax, 1.f);
    float poly = t * (0.254829592f + t * (-0.284496736f + t * (1.421413741f +
                 t * (-1.453152027f + t * 1.061405429f))));
    float e = fexp2(-ax * ax * 1.4426950408889634f);
    float erfv = 1.f - poly * e;
    erfv = copysignf(erfv, x);
    return 0.5f * v * (1.f + erfv);
}

// ---------------- f32 -> bf16 conversion (vectorized) ----------------
__global__ __launch_bounds__(256) void cvt_k(const float* __restrict__ in,
                                             bf16* __restrict__ out, int n4)
{
    int i = blockIdx.x * 256 + threadIdx.x;
    if (i >= n4) return;
    float4 v = reinterpret_cast<const float4*>(in)[i];
    bf16x4 o;
    o[0] = (bf16)v.x; o[1] = (bf16)v.y; o[2] = (bf16)v.z; o[3] = (bf16)v.w;
    reinterpret_cast<bf16x4*>(out)[i] = o;
}

// ---------------- embedding ----------------
__global__ void embed_k(const int* __restrict__ src, const float* __restrict__ emb,
                        const float* __restrict__ cls, float* __restrict__ x,
                        bf16* __restrict__ xb)
{
    long i = (long)blockIdx.x * blockDim.x + threadIdx.x;
    if (i >= (long)B * L * D) return;
    int d = (int)(i % D);
    long bl = i / D;
    int l = (int)(bl % L);
    int b = (int)(bl / L);
    float v = (l == 0) ? cls[d] : emb[(long)src[b * S + (l - 1)] * D + d];
    x[i] = v;
    xb[i] = (bf16)v;
}

// ---------------- MFMA bf16 GEMM: C[MP,N] = A[MP,K] @ W[N,K]^T + bias ----------
// RT = rows per tile (128: 4 waves 2x2 each 64x64; 64: 4 waves 1x4 each 64x32).
template<int ACT, int OBF, int BIAS, int RT>
__global__ __launch_bounds__(256) void mgemm(const bf16* __restrict__ A,
                                             const bf16* __restrict__ W,
                                             const float* __restrict__ bias,
                                             float* __restrict__ Cf,
                                             bf16* __restrict__ Cb,
                                             int N, int K, int LDA)
{
    __shared__ bf16 Asl[RT * 32];
    __shared__ bf16 Bsl[128 * 32];
    int tid = threadIdx.x;
    int m0 = blockIdx.y * RT;
    int n0 = blockIdx.x * 128;
    int lane = tid & 63;
    int w = tid >> 6;
    int wbase = tid & ~63;
    int kb = (lane >> 4) * 8;
    int rsel = lane & 15;
    constexpr int FJ = (RT == 128) ? 4 : 2;
    constexpr int CW = (RT == 128) ? 64 : 32;   // cols per wave
    int wr, wc;
    if constexpr (RT == 128) { wr = w >> 1; wc = w & 1; }
    else                     { wr = 0;      wc = w;     }
    f32x4 acc[4][FJ] = {};

    for (int k0 = 0; k0 < K; k0 += 32) {
        if constexpr (RT == 128) {
#pragma unroll
            for (int r = 0; r < 2; r++) {
                int s = r * 256 + tid;
                int sb = r * 256 + wbase;
                gld16(A + (size_t)(m0 + (s >> 2)) * LDA + k0 + (s & 3) * 8, &Asl[(size_t)sb * 8]);
                gld16(W + (size_t)(n0 + (s >> 2)) * LDA + k0 + (s & 3) * 8, &Bsl[(size_t)sb * 8]);
            }
        } else {
            gld16(A + (size_t)(m0 + (tid >> 2)) * LDA + k0 + (tid & 3) * 8, &Asl[(size_t)wbase * 8]);
#pragma unroll
            for (int r = 0; r < 2; r++) {
                int s = r * 256 + tid;
                int sb = r * 256 + wbase;
                gld16(W + (size_t)(n0 + (s >> 2)) * LDA + k0 + (s & 3) * 8, &Bsl[(size_t)sb * 8]);
            }
        }
        __syncthreads();
        bf16x8 af[4], bfr[FJ];
#pragma unroll
        for (int fi = 0; fi < 4; fi++)
            af[fi] = *reinterpret_cast<const bf16x8*>(&Asl[(wr * 64 + fi * 16 + rsel) * 32 + kb]);
#pragma unroll
        for (int fj = 0; fj < FJ; fj++)
            bfr[fj] = *reinterpret_cast<const bf16x8*>(&Bsl[(wc * CW + fj * 16 + rsel) * 32 + kb]);
#pragma unroll
        for (int fi = 0; fi < 4; fi++)
#pragma unroll
            for (int fj = 0; fj < FJ; fj++)
                acc[fi][fj] = __builtin_amdgcn_mfma_f32_16x16x32_bf16(af[fi], bfr[fj], acc[fi][fj], 0, 0, 0);
        __syncthreads();
    }
    int rowb = (lane >> 4) * 4;
    int colb = lane & 15;
#pragma unroll
    for (int fi = 0; fi < 4; fi++) {
#pragma unroll
        for (int fj = 0; fj < FJ; fj++) {
            int col = n0 + wc * CW + fj * 16 + colb;
            float bsv = BIAS ? bias[col] : 0.f;
#pragma unroll
            for (int i = 0; i < 4; i++) {
                int row = m0 + wr * 64 + fi * 16 + rowb + i;
                float v = acc[fi][fj][i] + bsv;
                if (ACT) v = fast_gelu(v);
                if (OBF) Cb[(size_t)row * N + col] = (bf16)v;
                else     Cf[(size_t)row * N + col] = v;
            }
        }
    }
}

// ---------------- MFMA flash attention v7: 2 q-tiles share K/V pipeline -------
__global__ __launch_bounds__(256) void fattn_k(const bf16* __restrict__ qkv,
                                               const float* __restrict__ rel_emb_l,
                                               const unsigned char* __restrict__ pad,
                                               bf16* __restrict__ ob)
{
    constexpr int PIT = 72;
    __shared__ bf16 Vt[2][64 * PIT];       // V^T[d][k ^ ((d>>3)<<3)]
    __shared__ bf16 Psh[4][2][16 * PIT];   // per-wave, per-qq P[q][kv]
    __shared__ float bias2s[2 * MAXD + 1];
    __shared__ float colm[2][64];

    const int bh = blockIdx.x;
    const int qt = blockIdx.y;
    const int h = bh & 7, b = bh >> 3;
    const int q0 = qt * 128;
    const int tid = threadIdx.x;
    const int lane = tid & 63;
    const int w = tid >> 6;
    const int ln15 = lane & 15, g4 = lane >> 4;
    const int kb8 = g4 * 8;
    constexpr float LOG2E = 1.4426950408889634f;
    constexpr float C2 = 0.125f * LOG2E;

    const char* base = (const char*)qkv + (size_t)(b * L) * 3072 + (size_t)h * (HD * 2);

    for (int i = tid; i < 2 * MAXD + 1; i += 256) bias2s[i] = rel_emb_l[i * H + h] * LOG2E;
    if (tid < 64) colm[0][tid] = (tid > 0 && pad[(size_t)b * S + tid - 1]) ? -1e9f : 0.f;

    int qrow[2];
    bf16x8 qa[2][2];
#pragma unroll
    for (int qq = 0; qq < 2; qq++) {
        qrow[qq] = q0 + qq * 64 + w * 16 + ln15;
        qa[qq][0] = *(const bf16x8*)(base + (size_t)qrow[qq] * 3072 + g4 * 16);
        qa[qq][1] = *(const bf16x8*)(base + (size_t)qrow[qq] * 3072 + 64 + g4 * 16);
    }

    const int vr = tid >> 3;
    const int vd0 = (tid & 7) * 8;
    const int vsw = ((vd0 >> 3) & 7) << 3;

    { // prologue: stage V tile 0
        bf16x8 a = *(const bf16x8*)(base + (size_t)vr * 3072 + 2048 + vd0 * 2);
        bf16x8 c = *(const bf16x8*)(base + (size_t)(vr + 32) * 3072 + 2048 + vd0 * 2);
#pragma unroll
        for (int j = 0; j < 8; j++) {
            Vt[0][(vd0 + j) * PIT + (vr ^ vsw)] = a[j];
            Vt[0][(vd0 + j) * PIT + ((vr + 32) ^ vsw)] = c[j];
        }
    }
    bf16x8 kr[4][2];
#pragma unroll
    for (int fj = 0; fj < 4; fj++) {
        const char* rp = base + (size_t)(fj * 16 + ln15) * 3072 + 1024 + g4 * 16;
        kr[fj][0] = *(const bf16x8*)(rp);
        kr[fj][1] = *(const bf16x8*)(rp + 64);
    }
    LGKM_BARRIER();

    f32x4 oacc[2][4] = {};
    float m_prev[2] = {-1e30f, -1e30f};
    float l_sum[2] = {0.f, 0.f};

    for (int t = 0; t < 17; t++) {
        const int k0 = t * 64;
        const int k0n = (k0 + 64 > 1024) ? 1024 : (k0 + 64);
        const int cur = t & 1;

        bf16x8 vA = *(const bf16x8*)(base + (size_t)(k0n + vr) * 3072 + 2048 + vd0 * 2);
        bf16x8 vB = *(const bf16x8*)(base + (size_t)(k0n + vr + 32) * 3072 + 2048 + vd0 * 2);

        f32x4 sacc[2][4] = {};
#pragma unroll
        for (int qq = 0; qq < 2; qq++)
#pragma unroll
            for (int fj = 0; fj < 4; fj++) {
                sacc[qq][fj] = __builtin_amdgcn_mfma_f32_16x16x32_bf16(kr[fj][0], qa[qq][0], sacc[qq][fj], 0, 0, 0);
                sacc[qq][fj] = __builtin_amdgcn_mfma_f32_16x16x32_bf16(kr[fj][1], qa[qq][1], sacc[qq][fj], 0, 0, 0);
            }
#pragma unroll
        for (int fj = 0; fj < 4; fj++) {
            const char* rp = base + (size_t)(k0n + fj * 16 + ln15) * 3072 + 1024 + g4 * 16;
            kr[fj][0] = *(const bf16x8*)(rp);
            kr[fj][1] = *(const bf16x8*)(rp + 64);
        }

        f32x4 cm[4];
#pragma unroll
        for (int fj = 0; fj < 4; fj++)
            cm[fj] = *(const f32x4*)&colm[cur][fj * 16 + g4 * 4];

#pragma unroll
        for (int qq = 0; qq < 2; qq++) {
            float sv[4][4];
            const int relbw = k0 - q0 - qq * 64 - w * 16;
            if (relbw >= MAXD + 15 || relbw <= -MAXD - 63) {
                const float bu = bias2s[relbw > 0 ? 2 * MAXD : 0];
#pragma unroll
                for (int fj = 0; fj < 4; fj++)
#pragma unroll
                    for (int i = 0; i < 4; i++)
                        sv[fj][i] = fmaf(sacc[qq][fj][i], C2, bu + cm[fj][i]);
            } else {
                const int relb = k0 - qrow[qq];
#pragma unroll
                for (int fj = 0; fj < 4; fj++)
#pragma unroll
                    for (int i = 0; i < 4; i++) {
                        int rel = relb + fj * 16 + g4 * 4 + i;
                        rel = rel < -MAXD ? -MAXD : (rel > MAXD ? MAXD : rel);
                        sv[fj][i] = fmaf(sacc[qq][fj][i], C2, bias2s[rel + MAXD] + cm[fj][i]);
                    }
            }

            float mx = sv[0][0];
#pragma unroll
            for (int fj = 0; fj < 4; fj++)
#pragma unroll
                for (int i = 0; i < 4; i++) mx = fmaxf(mx, sv[fj][i]);
            mx = fmaxf(mx, __shfl_xor(mx, 16));
            mx = fmaxf(mx, __shfl_xor(mx, 32));
            const float mnew = fmaxf(m_prev[qq], mx);
            const float corr = fexp2(m_prev[qq] - mnew);
            float rsum = 0.f;
            float pb[4][4];
#pragma unroll
            for (int fj = 0; fj < 4; fj++)
#pragma unroll
                for (int i = 0; i < 4; i++) {
                    float p = fexp2(sv[fj][i] - mnew);
                    pb[fj][i] = p;
                    rsum += p;
                }
            rsum += __shfl_xor(rsum, 16);
            rsum += __shfl_xor(rsum, 32);
            l_sum[qq] = l_sum[qq] * corr + rsum;
            m_prev[qq] = mnew;
#pragma unroll
            for (int fd = 0; fd < 4; fd++) oacc[qq][fd] *= corr;

#pragma unroll
            for (int fj = 0; fj < 4; fj++) {
                union { bf16 hh[4]; unsigned long long u; } pk;
                pk.hh[0] = (bf16)pb[fj][0]; pk.hh[1] = (bf16)pb[fj][1];
                pk.hh[2] = (bf16)pb[fj][2]; pk.hh[3] = (bf16)pb[fj][3];
                *(unsigned long long*)&Psh[w][qq][ln15 * PIT + fj * 16 + g4 * 4] = pk.u;
            }
        }

#pragma unroll
        for (int j = 0; j < 8; j++) {
            Vt[cur ^ 1][(vd0 + j) * PIT + (vr ^ vsw)] = vA[j];
            Vt[cur ^ 1][(vd0 + j) * PIT + ((vr + 32) ^ vsw)] = vB[j];
        }
        if (tid < 64) {
            int gk = k0 + 64 + tid;
            int pi = (gk <= 1024) ? gk - 1 : 0;
            colm[cur ^ 1][tid] = (gk > 1024 || pad[(size_t)b * S + pi]) ? -1e9f : 0.f;
        }

        LGKM_BARRIER();   // D1

        bf16x8 pa[2][2];
#pragma unroll
        for (int qq = 0; qq < 2; qq++) {
            pa[qq][0] = *(const bf16x8*)&Psh[w][qq][ln15 * PIT + kb8];
            pa[qq][1] = *(const bf16x8*)&Psh[w][qq][ln15 * PIT + 32 + kb8];
        }
#pragma unroll
        for (int fd = 0; fd < 4; fd++) {
            const int d = fd * 16 + ln15;
            const int vx = ((d >> 3) & 7) << 3;
            bf16x8 af0 = *(const bf16x8*)&Vt[cur][d * PIT + (kb8 ^ vx)];
            bf16x8 af1 = *(const bf16x8*)&Vt[cur][d * PIT + ((32 + kb8) ^ vx)];
            oacc[0][fd] = __builtin_amdgcn_mfma_f32_16x16x32_bf16(af0, pa[0][0], oacc[0][fd], 0, 0, 0);
            oacc[0][fd] = __builtin_amdgcn_mfma_f32_16x16x32_bf16(af1, pa[0][1], oacc[0][fd], 0, 0, 0);
            oacc[1][fd] = __builtin_amdgcn_mfma_f32_16x16x32_bf16(af0, pa[1][0], oacc[1][fd], 0, 0, 0);
            oacc[1][fd] = __builtin_amdgcn_mfma_f32_16x16x32_bf16(af1, pa[1][1], oacc[1][fd], 0, 0, 0);
        }
        LGKM_BARRIER();   // D2
    }

#pragma unroll
    for (int qq = 0; qq < 2; qq++) {
        if (qrow[qq] < L) {
            const float inv = 1.f / l_sum[qq];
            bf16* op = ob + (size_t)(b * L + qrow[qq]) * D + h * HD + g4 * 4;
#pragma unroll
            for (int fd = 0; fd < 4; fd++) {
                bf16x4 r;
#pragma unroll
                for (int i = 0; i < 4; i++) r[i] = (bf16)(oacc[qq][fd][i] * inv);
                *(bf16x4*)(op + fd * 16) = r;
            }
        }
    }
}

// ---------------- out = LayerNorm(xin + rin), f32 + bf16 copies ----------------
__global__ __launch_bounds__(256) void add_ln_k(const float* __restrict__ xin,
                                                const float* __restrict__ rin,
                                                const float* __restrict__ g,
                                                const float* __restrict__ bb,
                                                float* __restrict__ out,
                                                bf16* __restrict__ outb)
{
    int row = blockIdx.x;
    __shared__ float red[8];
    int tid = threadIdx.x;
    const float* xp = xin + (size_t)row * D;
    const float* rp = rin + (size_t)row * D;
    float v0 = xp[tid] + rp[tid];
    float v1 = xp[tid + 256] + rp[tid + 256];
    float s = v0 + v1;
    for (int off = 32; off; off >>= 1) s += __shfl_down(s, off, 64);
    int lane = tid & 63, wid = tid >> 6;
    if (lane == 0) red[wid] = s;
    __syncthreads();
    if (tid == 0) red[0] = red[0] + red[1] + red[2] + red[3];
    __syncthreads();
    float mean = red[0] * (1.f / D);
    float d0 = v0 - mean, d1 = v1 - mean;
    float sq = d0 * d0 + d1 * d1;
    for (int off = 32; off; off >>= 1) sq += __shfl_down(sq, off, 64);
    if (lane == 0) red[4 + wid] = sq;
    __syncthreads();
    if (tid == 0) red[4] = red[4] + red[5] + red[6] + red[7];
    __syncthreads();
    float rs = rsqrtf(red[4] * (1.f / D) + 1e-5f);
    float r0 = d0 * rs * g[tid] + bb[tid];
    float r1 = d1 * rs * g[tid + 256] + bb[tid + 256];
    out[(size_t)row * D + tid] = r0;
    out[(size_t)row * D + tid + 256] = r1;
    outb[(size_t)row * D + tid] = (bf16)r0;
    outb[(size_t)row * D + tid + 256] = (bf16)r1;
}

// ---------------- final LN (row 0 only) + classifier ----------------
__global__ __launch_bounds__(256) void cls_k(const float* __restrict__ x,
                                             const float* __restrict__ ng,
                                             const float* __restrict__ nb,
                                             const float* __restrict__ cw,
                                             const float* __restrict__ cb,
                                             float* __restrict__ out)
{
    int b = blockIdx.x;
    __shared__ float xn[D];
    __shared__ float red[8];
    int tid = threadIdx.x;
    const float* xp = x + (size_t)(b * L) * D;
    float v0 = xp[tid], v1 = xp[tid + 256];
    float s = v0 + v1;
    for (int off = 32; off; off >>= 1) s += __shfl_down(s, off, 64);
    int lane = tid & 63, wid = tid >> 6;
    if (lane == 0) red[wid] = s;
    __syncthreads();
    if (tid == 0) red[0] = red[0] + red[1] + red[2] + red[3];
    __syncthreads();
    float mean = red[0] * (1.f / D);
    float d0 = v0 - mean, d1 = v1 - mean;
    float sq = d0 * d0 + d1 * d1;
    for (int off = 32; off; off >>= 1) sq += __shfl_down(sq, off, 64);
    if (lane == 0) red[4 + wid] = sq;
    __syncthreads();
    if (tid == 0) red[4] = red[4] + red[5] + red[6] + red[7];
    __syncthreads();
    float rs = rsqrtf(red[4] * (1.f / D) + 1e-5f);
    xn[tid] = d0 * rs * ng[tid] + nb[tid];
    xn[tid + 256] = d1 * rs * ng[tid + 256] + nb[tid + 256];
    __syncthreads();
    for (int o = tid; o < OUTLEN * NC; o += 256) {
        float acc = cb[o];
        const float* wp = cw + (size_t)o * D;
        for (int d = 0; d < D; d++) acc += xn[d] * wp[d];
        out[b * OUTLEN * NC + o] = acc;
    }
}

extern "C" void kernel_launch(void* const* d_in, const int* in_sizes, int n_in,
                              void* d_out, int out_size, void* d_ws, size_t ws_size,
                              hipStream_t stream) {
    const int* src = (const int*)d_in[0];
    const unsigned char* pad = (const unsigned char*)d_in[1];
    const float* emb = (const float*)d_in[2];
    const float* cls_token = (const float*)d_in[3];
    const float* qkv_w = (const float*)d_in[4];
    const float* qkv_b = (const float*)d_in[5];
    const float* out_w = (const float*)d_in[6];
    const float* out_b = (const float*)d_in[7];
    const float* rel_emb = (const float*)d_in[8];
    const float* ln1_g = (const float*)d_in[9];
    const float* ln1_b = (const float*)d_in[10];
    const float* w1 = (const float*)d_in[11];
    const float* b1 = (const float*)d_in[12];
    const float* w2 = (const float*)d_in[13];
    const float* b2 = (const float*)d_in[14];
    const float* ln2_g = (const float*)d_in[15];
    const float* ln2_b = (const float*)d_in[16];
    const float* norm_g = (const float*)d_in[17];
    const float* norm_b = (const float*)d_in[18];
    const float* cls_w = (const float*)d_in[19];
    const float* cls_b = (const float*)d_in[20];
    float* out = (float*)d_out;

    char* ws = (char*)d_ws;
    size_t off = 0;
    float* x   = (float*)(ws + off); off += (size_t)MP * D * 4;
    bf16*  xb  = (bf16*) (ws + off); off += (size_t)MP * D * 2;
    float* x2  = (float*)(ws + off); off += (size_t)MP * D * 4;
    bf16*  x2b = (bf16*) (ws + off); off += (size_t)MP * D * 2;
    char*  R   = ws + off;           off += (size_t)MP * 3 * D * 4; // qkvb | (hb + p)
    bf16*  qkvb = (bf16*)R;                              // MP*3D*2
    bf16*  hb  = (bf16*)R;                               // MP*FF*2 (after attn)
    float* p   = (float*)(R + (size_t)MP * FF * 2);      // MP*D*4
    bf16*  obf = (bf16*) (ws + off); off += (size_t)MP * D * 2;

    const size_t WQ = (size_t)NL * 3 * D * D;
    const size_t WO = (size_t)NL * D * D;
    const size_t W1E = (size_t)NL * FF * D;
    const size_t W2E = (size_t)NL * D * FF;
    const size_t WALL = WQ + WO + W1E + W2E;
    bool all_w = (off + WALL * 2) <= ws_size;

    bf16 *wq_a = nullptr, *wo_a = nullptr, *w1_a = nullptr, *w2_a = nullptr, *wbuf = nullptr;
    if (all_w) {
        wq_a = (bf16*)(ws + off);
        wo_a = wq_a + WQ;
        w1_a = wo_a + WO;
        w2_a = w1_a + W1E;
        int n4;
        n4 = (int)(WQ / 4);  cvt_k<<<dim3((n4 + 255) / 256), 256, 0, stream>>>(qkv_w, wq_a, n4);
        n4 = (int)(WO / 4);  cvt_k<<<dim3((n4 + 255) / 256), 256, 0, stream>>>(out_w, wo_a, n4);
        n4 = (int)(W1E / 4); cvt_k<<<dim3((n4 + 255) / 256), 256, 0, stream>>>(w1, w1_a, n4);
        n4 = (int)(W2E / 4); cvt_k<<<dim3((n4 + 255) / 256), 256, 0, stream>>>(w2, w2_a, n4);
    } else {
        wbuf = (bf16*)(ws + off); // per-layer rotating buffer
    }

    const int M = B * L;
    {
        long total = (long)B * L * D;
        embed_k<<<dim3((unsigned)((total + 255) / 256)), 256, 0, stream>>>(src, emb, cls_token, x, xb);
    }
    for (int l = 0; l < NL; l++) {
        const float* qb  = qkv_b + (size_t)l * 3 * D;
        const float* obi = out_b + (size_t)l * D;
        const float* re  = rel_emb + (size_t)l * (2 * MAXD + 1) * H;
        const float* g1  = ln1_g + (size_t)l * D;
        const float* be1 = ln1_b + (size_t)l * D;
        const float* B1p = b1 + (size_t)l * FF;
        const float* B2p = b2 + (size_t)l * D;
        const float* g2  = ln2_g + (size_t)l * D;
        const float* be2 = ln2_b + (size_t)l * D;

        const bf16 *wqb, *wob, *w1b, *w2b;
        if (all_w) {
            wqb = wq_a + (size_t)l * 3 * D * D;
            wob = wo_a + (size_t)l * D * D;
            w1b = w1_a + (size_t)l * FF * D;
            w2b = w2_a + (size_t)l * D * FF;
        } else {
            bf16* wp_ = wbuf;
            wqb = wp_;            wp_ += 3 * D * D;
            wob = wp_;            wp_ += D * D;
            w1b = wp_;            wp_ += FF * D;
            w2b = wp_;
            int n4;
            n4 = 3 * D * D / 4; cvt_k<<<dim3((n4 + 255) / 256), 256, 0, stream>>>(qkv_w + (size_t)l * 3 * D * D, (bf16*)wqb, n4);
            n4 = D * D / 4;     cvt_k<<<dim3((n4 + 255) / 256), 256, 0, stream>>>(out_w + (size_t)l * D * D, (bf16*)wob, n4);
            n4 = FF * D / 4;    cvt_k<<<dim3((n4 + 255) / 256), 256, 0, stream>>>(w1 + (size_t)l * FF * D, (bf16*)w1b, n4);
            n4 = D * FF / 4;    cvt_k<<<dim3((n4 + 255) / 256), 256, 0, stream>>>(w2 + (size_t)l * D * FF, (bf16*)w2b, n4);
        }

        mgemm<0, 1, 1, 128><<<dim3(3 * D / 128, MP / 128), 256, 0, stream>>>(xb, wqb, qb, nullptr, qkvb, 3 * D, D, D);
        fattn_k<<<dim3(B * H, 9), 256, 0, stream>>>(qkvb, re, pad, obf);
        mgemm<0, 0, 1, 64><<<dim3(D / 128, MP / 64), 256, 0, stream>>>(obf, wob, obi, p, nullptr, D, D, D);
        add_ln_k<<<dim3(M), 256, 0, stream>>>(x, p, g1, be1, x2, x2b);
        mgemm<1, 1, 1, 128><<<dim3(FF / 128, MP / 128), 256, 0, stream>>>(x2b, w1b, B1p, nullptr, hb, FF, D, D);
        mgemm<0, 0, 1, 64><<<dim3(D / 128, MP / 64), 256, 0, stream>>>(hb, w2b, B2p, p, nullptr, D, FF, FF);
        add_ln_k<<<dim3(M), 256, 0, stream>>>(x2, p, g2, be2, x, xb);
    }
    cls_k<<<dim3(B), 256, 0, stream>>>(x, norm_g, norm_b, cls_w, cls_b, out);
}

// Round 14
// 1484.813 us; speedup vs baseline: 1.2038x; 1.0492x over previous
//
#include <hip/hip_runtime.h>
#include <hip/hip_bf16.h>
#include <stdint.h>

#define B 8
#define S 1024
#define L 1025
#define D 512
#define H 8
#define HD 64
#define NL 6
#define FF 2048
#define MAXD 64
#define OUTLEN 8
#define NC 10

#define MP 8320   // 65 * 128, padded M

typedef __bf16 bf16;
typedef __bf16 bf16x8 __attribute__((ext_vector_type(8)));
typedef __bf16 bf16x4 __attribute__((ext_vector_type(4)));
typedef float f32x4 __attribute__((ext_vector_type(4)));

__device__ __forceinline__ float fexp2(float x) { return __builtin_amdgcn_exp2f(x); }

// barrier WITHOUT the vmcnt(0) drain
#define LGKM_BARRIER() asm volatile("s_waitcnt lgkmcnt(0)\ns_barrier" ::: "memory")

__device__ __forceinline__ void gld16(const void* g, void* l) {
    __builtin_amdgcn_global_load_lds(
        (const __attribute__((address_space(1))) unsigned int*)g,
        (__attribute__((address_space(3))) unsigned int*)l,
        16, 0, 0);
}

// GELU with A&S 7.1.26 erf (|err| <= 1.5e-7), no libm call
__device__ __forceinline__ float fast_gelu(float v) {
    float x = v * 0.70710678118654752f;
    float ax = fabsf(x);
    float t = 1.f / fmaf(0.3275911f, ax, 1.f);
    float poly = t * (0.254829592f + t * (-0.284496736f + t * (1.421413741f +
                 t * (-1.453152027f + t * 1.061405429f))));
    float e = fexp2(-ax * ax * 1.4426950408889634f);
    float erfv = 1.f - poly * e;
    erfv = copysignf(erfv, x);
    return 0.5f * v * (1.f + erfv);
}

// ---------------- f32 -> bf16 conversion (vectorized) ----------------
__global__ __launch_bounds__(256) void cvt_k(const float* __restrict__ in,
                                             bf16* __restrict__ out, int n4)
{
    int i = blockIdx.x * 256 + threadIdx.x;
    if (i >= n4) return;
    float4 v = reinterpret_cast<const float4*>(in)[i];
    bf16x4 o;
    o[0] = (bf16)v.x; o[1] = (bf16)v.y; o[2] = (bf16)v.z; o[3] = (bf16)v.w;
    reinterpret_cast<bf16x4*>(out)[i] = o;
}

// ---------------- embedding ----------------
__global__ void embed_k(const int* __restrict__ src, const float* __restrict__ emb,
                        const float* __restrict__ cls, float* __restrict__ x,
                        bf16* __restrict__ xb)
{
    long i = (long)blockIdx.x * blockDim.x + threadIdx.x;
    if (i >= (long)B * L * D) return;
    int d = (int)(i % D);
    long bl = i / D;
    int l = (int)(bl % L);
    int b = (int)(bl / L);
    float v = (l == 0) ? cls[d] : emb[(long)src[b * S + (l - 1)] * D + d];
    x[i] = v;
    xb[i] = (bf16)v;
}

// ---------------- MFMA bf16 GEMM, 2-phase double-buffered LDS ----------------
// RT = rows per tile (128: 4 waves 2x2 each 64x64; 64: 4 waves 1x4 each 64x32).
// Per K-step: issue global_load_lds for tile t+1 -> compute tile t -> one
// __syncthreads (vmcnt drain commits staged buffer; lgkm drains ds_reads).
template<int ACT, int OBF, int BIAS, int RT>
__global__ __launch_bounds__(256) void mgemm(const bf16* __restrict__ A,
                                             const bf16* __restrict__ W,
                                             const float* __restrict__ bias,
                                             float* __restrict__ Cf,
                                             bf16* __restrict__ Cb,
                                             int N, int K, int LDA)
{
    __shared__ bf16 Asl[2][RT * 32];
    __shared__ bf16 Bsl[2][128 * 32];
    int tid = threadIdx.x;
    int m0 = blockIdx.y * RT;
    int n0 = blockIdx.x * 128;
    int lane = tid & 63;
    int w = tid >> 6;
    int wbase = tid & ~63;
    int kb = (lane >> 4) * 8;
    int rsel = lane & 15;
    constexpr int FJ = (RT == 128) ? 4 : 2;
    constexpr int CW = (RT == 128) ? 64 : 32;   // cols per wave
    int wr, wc;
    if constexpr (RT == 128) { wr = w >> 1; wc = w & 1; }
    else                     { wr = 0;      wc = w;     }
    f32x4 acc[4][FJ] = {};

    auto stage = [&](int buf, int k0) {
        if constexpr (RT == 128) {
#pragma unroll
            for (int r = 0; r < 2; r++) {
                int s = r * 256 + tid;
                int sb = r * 256 + wbase;
                gld16(A + (size_t)(m0 + (s >> 2)) * LDA + k0 + (s & 3) * 8, &Asl[buf][(size_t)sb * 8]);
                gld16(W + (size_t)(n0 + (s >> 2)) * LDA + k0 + (s & 3) * 8, &Bsl[buf][(size_t)sb * 8]);
            }
        } else {
            gld16(A + (size_t)(m0 + (tid >> 2)) * LDA + k0 + (tid & 3) * 8, &Asl[buf][(size_t)wbase * 8]);
#pragma unroll
            for (int r = 0; r < 2; r++) {
                int s = r * 256 + tid;
                int sb = r * 256 + wbase;
                gld16(W + (size_t)(n0 + (s >> 2)) * LDA + k0 + (s & 3) * 8, &Bsl[buf][(size_t)sb * 8]);
            }
        }
    };

    stage(0, 0);
    __syncthreads();

    for (int k0 = 0; k0 < K; k0 += 32) {
        int cur = (k0 >> 5) & 1;
        if (k0 + 32 < K) stage(cur ^ 1, k0 + 32);   // async: lands before next barrier
        bf16x8 af[4], bfr[FJ];
#pragma unroll
        for (int fi = 0; fi < 4; fi++)
            af[fi] = *reinterpret_cast<const bf16x8*>(&Asl[cur][(wr * 64 + fi * 16 + rsel) * 32 + kb]);
#pragma unroll
        for (int fj = 0; fj < FJ; fj++)
            bfr[fj] = *reinterpret_cast<const bf16x8*>(&Bsl[cur][(wc * CW + fj * 16 + rsel) * 32 + kb]);
#pragma unroll
        for (int fi = 0; fi < 4; fi++)
#pragma unroll
            for (int fj = 0; fj < FJ; fj++)
                acc[fi][fj] = __builtin_amdgcn_mfma_f32_16x16x32_bf16(af[fi], bfr[fj], acc[fi][fj], 0, 0, 0);
        __syncthreads();   // vmcnt drain commits staged buffer; all reads of cur done
    }
    int rowb = (lane >> 4) * 4;
    int colb = lane & 15;
#pragma unroll
    for (int fi = 0; fi < 4; fi++) {
#pragma unroll
        for (int fj = 0; fj < FJ; fj++) {
            int col = n0 + wc * CW + fj * 16 + colb;
            float bsv = BIAS ? bias[col] : 0.f;
#pragma unroll
            for (int i = 0; i < 4; i++) {
                int row = m0 + wr * 64 + fi * 16 + rowb + i;
                float v = acc[fi][fj][i] + bsv;
                if (ACT) v = fast_gelu(v);
                if (OBF) Cb[(size_t)row * N + col] = (bf16)v;
                else     Cf[(size_t)row * N + col] = v;
            }
        }
    }
}

// ---------------- MFMA flash attention v7: 2 q-tiles share K/V pipeline -------
__global__ __launch_bounds__(256) void fattn_k(const bf16* __restrict__ qkv,
                                               const float* __restrict__ rel_emb_l,
                                               const unsigned char* __restrict__ pad,
                                               bf16* __restrict__ ob)
{
    constexpr int PIT = 72;
    __shared__ bf16 Vt[2][64 * PIT];       // V^T[d][k ^ ((d>>3)<<3)]
    __shared__ bf16 Psh[4][2][16 * PIT];   // per-wave, per-qq P[q][kv]
    __shared__ float bias2s[2 * MAXD + 1];
    __shared__ float colm[2][64];

    const int bh = blockIdx.x;
    const int qt = blockIdx.y;
    const int h = bh & 7, b = bh >> 3;
    const int q0 = qt * 128;
    const int tid = threadIdx.x;
    const int lane = tid & 63;
    const int w = tid >> 6;
    const int ln15 = lane & 15, g4 = lane >> 4;
    const int kb8 = g4 * 8;
    constexpr float LOG2E = 1.4426950408889634f;
    constexpr float C2 = 0.125f * LOG2E;

    const char* base = (const char*)qkv + (size_t)(b * L) * 3072 + (size_t)h * (HD * 2);

    for (int i = tid; i < 2 * MAXD + 1; i += 256) bias2s[i] = rel_emb_l[i * H + h] * LOG2E;
    if (tid < 64) colm[0][tid] = (tid > 0 && pad[(size_t)b * S + tid - 1]) ? -1e9f : 0.f;

    int qrow[2];
    bf16x8 qa[2][2];
#pragma unroll
    for (int qq = 0; qq < 2; qq++) {
        qrow[qq] = q0 + qq * 64 + w * 16 + ln15;
        qa[qq][0] = *(const bf16x8*)(base + (size_t)qrow[qq] * 3072 + g4 * 16);
        qa[qq][1] = *(const bf16x8*)(base + (size_t)qrow[qq] * 3072 + 64 + g4 * 16);
    }

    const int vr = tid >> 3;
    const int vd0 = (tid & 7) * 8;
    const int vsw = ((vd0 >> 3) & 7) << 3;

    { // prologue: stage V tile 0
        bf16x8 a = *(const bf16x8*)(base + (size_t)vr * 3072 + 2048 + vd0 * 2);
        bf16x8 c = *(const bf16x8*)(base + (size_t)(vr + 32) * 3072 + 2048 + vd0 * 2);
#pragma unroll
        for (int j = 0; j < 8; j++) {
            Vt[0][(vd0 + j) * PIT + (vr ^ vsw)] = a[j];
            Vt[0][(vd0 + j) * PIT + ((vr + 32) ^ vsw)] = c[j];
        }
    }
    bf16x8 kr[4][2];
#pragma unroll
    for (int fj = 0; fj < 4; fj++) {
        const char* rp = base + (size_t)(fj * 16 + ln15) * 3072 + 1024 + g4 * 16;
        kr[fj][0] = *(const bf16x8*)(rp);
        kr[fj][1] = *(const bf16x8*)(rp + 64);
    }
    LGKM_BARRIER();

    f32x4 oacc[2][4] = {};
    float m_prev[2] = {-1e30f, -1e30f};
    float l_sum[2] = {0.f, 0.f};

    for (int t = 0; t < 17; t++) {
        const int k0 = t * 64;
        const int k0n = (k0 + 64 > 1024) ? 1024 : (k0 + 64);
        const int cur = t & 1;

        bf16x8 vA = *(const bf16x8*)(base + (size_t)(k0n + vr) * 3072 + 2048 + vd0 * 2);
        bf16x8 vB = *(const bf16x8*)(base + (size_t)(k0n + vr + 32) * 3072 + 2048 + vd0 * 2);

        f32x4 sacc[2][4] = {};
#pragma unroll
        for (int qq = 0; qq < 2; qq++)
#pragma unroll
            for (int fj = 0; fj < 4; fj++) {
                sacc[qq][fj] = __builtin_amdgcn_mfma_f32_16x16x32_bf16(kr[fj][0], qa[qq][0], sacc[qq][fj], 0, 0, 0);
                sacc[qq][fj] = __builtin_amdgcn_mfma_f32_16x16x32_bf16(kr[fj][1], qa[qq][1], sacc[qq][fj], 0, 0, 0);
            }
#pragma unroll
        for (int fj = 0; fj < 4; fj++) {
            const char* rp = base + (size_t)(k0n + fj * 16 + ln15) * 3072 + 1024 + g4 * 16;
            kr[fj][0] = *(const bf16x8*)(rp);
            kr[fj][1] = *(const bf16x8*)(rp + 64);
        }

        f32x4 cm[4];
#pragma unroll
        for (int fj = 0; fj < 4; fj++)
            cm[fj] = *(const f32x4*)&colm[cur][fj * 16 + g4 * 4];

#pragma unroll
        for (int qq = 0; qq < 2; qq++) {
            float sv[4][4];
            const int relbw = k0 - q0 - qq * 64 - w * 16;
            if (relbw >= MAXD + 15 || relbw <= -MAXD - 63) {
                const float bu = bias2s[relbw > 0 ? 2 * MAXD : 0];
#pragma unroll
                for (int fj = 0; fj < 4; fj++)
#pragma unroll
                    for (int i = 0; i < 4; i++)
                        sv[fj][i] = fmaf(sacc[qq][fj][i], C2, bu + cm[fj][i]);
            } else {
                const int relb = k0 - qrow[qq];
#pragma unroll
                for (int fj = 0; fj < 4; fj++)
#pragma unroll
                    for (int i = 0; i < 4; i++) {
                        int rel = relb + fj * 16 + g4 * 4 + i;
                        rel = rel < -MAXD ? -MAXD : (rel > MAXD ? MAXD : rel);
                        sv[fj][i] = fmaf(sacc[qq][fj][i], C2, bias2s[rel + MAXD] + cm[fj][i]);
                    }
            }

            float mx = sv[0][0];
#pragma unroll
            for (int fj = 0; fj < 4; fj++)
#pragma unroll
                for (int i = 0; i < 4; i++) mx = fmaxf(mx, sv[fj][i]);
            mx = fmaxf(mx, __shfl_xor(mx, 16));
            mx = fmaxf(mx, __shfl_xor(mx, 32));
            const float mnew = fmaxf(m_prev[qq], mx);
            const float corr = fexp2(m_prev[qq] - mnew);
            float rsum = 0.f;
            float pb[4][4];
#pragma unroll
            for (int fj = 0; fj < 4; fj++)
#pragma unroll
                for (int i = 0; i < 4; i++) {
                    float p = fexp2(sv[fj][i] - mnew);
                    pb[fj][i] = p;
                    rsum += p;
                }
            rsum += __shfl_xor(rsum, 16);
            rsum += __shfl_xor(rsum, 32);
            l_sum[qq] = l_sum[qq] * corr + rsum;
            m_prev[qq] = mnew;
#pragma unroll
            for (int fd = 0; fd < 4; fd++) oacc[qq][fd] *= corr;

#pragma unroll
            for (int fj = 0; fj < 4; fj++) {
                union { bf16 hh[4]; unsigned long long u; } pk;
                pk.hh[0] = (bf16)pb[fj][0]; pk.hh[1] = (bf16)pb[fj][1];
                pk.hh[2] = (bf16)pb[fj][2]; pk.hh[3] = (bf16)pb[fj][3];
                *(unsigned long long*)&Psh[w][qq][ln15 * PIT + fj * 16 + g4 * 4] = pk.u;
            }
        }

#pragma unroll
        for (int j = 0; j < 8; j++) {
            Vt[cur ^ 1][(vd0 + j) * PIT + (vr ^ vsw)] = vA[j];
            Vt[cur ^ 1][(vd0 + j) * PIT + ((vr + 32) ^ vsw)] = vB[j];
        }
        if (tid < 64) {
            int gk = k0 + 64 + tid;
            int pi = (gk <= 1024) ? gk - 1 : 0;
            colm[cur ^ 1][tid] = (gk > 1024 || pad[(size_t)b * S + pi]) ? -1e9f : 0.f;
        }

        LGKM_BARRIER();   // D1

        bf16x8 pa[2][2];
#pragma unroll
        for (int qq = 0; qq < 2; qq++) {
            pa[qq][0] = *(const bf16x8*)&Psh[w][qq][ln15 * PIT + kb8];
            pa[qq][1] = *(const bf16x8*)&Psh[w][qq][ln15 * PIT + 32 + kb8];
        }
#pragma unroll
        for (int fd = 0; fd < 4; fd++) {
            const int d = fd * 16 + ln15;
            const int vx = ((d >> 3) & 7) << 3;
            bf16x8 af0 = *(const bf16x8*)&Vt[cur][d * PIT + (kb8 ^ vx)];
            bf16x8 af1 = *(const bf16x8*)&Vt[cur][d * PIT + ((32 + kb8) ^ vx)];
            oacc[0][fd] = __builtin_amdgcn_mfma_f32_16x16x32_bf16(af0, pa[0][0], oacc[0][fd], 0, 0, 0);
            oacc[0][fd] = __builtin_amdgcn_mfma_f32_16x16x32_bf16(af1, pa[0][1], oacc[0][fd], 0, 0, 0);
            oacc[1][fd] = __builtin_amdgcn_mfma_f32_16x16x32_bf16(af0, pa[1][0], oacc[1][fd], 0, 0, 0);
            oacc[1][fd] = __builtin_amdgcn_mfma_f32_16x16x32_bf16(af1, pa[1][1], oacc[1][fd], 0, 0, 0);
        }
        LGKM_BARRIER();   // D2
    }

#pragma unroll
    for (int qq = 0; qq < 2; qq++) {
        if (qrow[qq] < L) {
            const float inv = 1.f / l_sum[qq];
            bf16* op = ob + (size_t)(b * L + qrow[qq]) * D + h * HD + g4 * 4;
#pragma unroll
            for (int fd = 0; fd < 4; fd++) {
                bf16x4 r;
#pragma unroll
                for (int i = 0; i < 4; i++) r[i] = (bf16)(oacc[qq][fd][i] * inv);
                *(bf16x4*)(op + fd * 16) = r;
            }
        }
    }
}

// ---------------- out = LayerNorm(xin + rin), f32 + bf16 copies ----------------
__global__ __launch_bounds__(256) void add_ln_k(const float* __restrict__ xin,
                                                const float* __restrict__ rin,
                                                const float* __restrict__ g,
                                                const float* __restrict__ bb,
                                                float* __restrict__ out,
                                                bf16* __restrict__ outb)
{
    int row = blockIdx.x;
    __shared__ float red[8];
    int tid = threadIdx.x;
    const float* xp = xin + (size_t)row * D;
    const float* rp = rin + (size_t)row * D;
    float v0 = xp[tid] + rp[tid];
    float v1 = xp[tid + 256] + rp[tid + 256];
    float s = v0 + v1;
    for (int off = 32; off; off >>= 1) s += __shfl_down(s, off, 64);
    int lane = tid & 63, wid = tid >> 6;
    if (lane == 0) red[wid] = s;
    __syncthreads();
    if (tid == 0) red[0] = red[0] + red[1] + red[2] + red[3];
    __syncthreads();
    float mean = red[0] * (1.f / D);
    float d0 = v0 - mean, d1 = v1 - mean;
    float sq = d0 * d0 + d1 * d1;
    for (int off = 32; off; off >>= 1) sq += __shfl_down(sq, off, 64);
    if (lane == 0) red[4 + wid] = sq;
    __syncthreads();
    if (tid == 0) red[4] = red[4] + red[5] + red[6] + red[7];
    __syncthreads();
    float rs = rsqrtf(red[4] * (1.f / D) + 1e-5f);
    float r0 = d0 * rs * g[tid] + bb[tid];
    float r1 = d1 * rs * g[tid + 256] + bb[tid + 256];
    out[(size_t)row * D + tid] = r0;
    out[(size_t)row * D + tid + 256] = r1;
    outb[(size_t)row * D + tid] = (bf16)r0;
    outb[(size_t)row * D + tid + 256] = (bf16)r1;
}

// ---------------- final LN (row 0 only) + classifier ----------------
__global__ __launch_bounds__(256) void cls_k(const float* __restrict__ x,
                                             const float* __restrict__ ng,
                                             const float* __restrict__ nb,
                                             const float* __restrict__ cw,
                                             const float* __restrict__ cb,
                                             float* __restrict__ out)
{
    int b = blockIdx.x;
    __shared__ float xn[D];
    __shared__ float red[8];
    int tid = threadIdx.x;
    const float* xp = x + (size_t)(b * L) * D;
    float v0 = xp[tid], v1 = xp[tid + 256];
    float s = v0 + v1;
    for (int off = 32; off; off >>= 1) s += __shfl_down(s, off, 64);
    int lane = tid & 63, wid = tid >> 6;
    if (lane == 0) red[wid] = s;
    __syncthreads();
    if (tid == 0) red[0] = red[0] + red[1] + red[2] + red[3];
    __syncthreads();
    float mean = red[0] * (1.f / D);
    float d0 = v0 - mean, d1 = v1 - mean;
    float sq = d0 * d0 + d1 * d1;
    for (int off = 32; off; off >>= 1) sq += __shfl_down(sq, off, 64);
    if (lane == 0) red[4 + wid] = sq;
    __syncthreads();
    if (tid == 0) red[4] = red[4] + red[5] + red[6] + red[7];
    __syncthreads();
    float rs = rsqrtf(red[4] * (1.f / D) + 1e-5f);
    xn[tid] = d0 * rs * ng[tid] + nb[tid];
    xn[tid + 256] = d1 * rs * ng[tid + 256] + nb[tid + 256];
    __syncthreads();
    for (int o = tid; o < OUTLEN * NC; o += 256) {
        float acc = cb[o];
        const float* wp = cw + (size_t)o * D;
        for (int d = 0; d < D; d++) acc += xn[d] * wp[d];
        out[b * OUTLEN * NC + o] = acc;
    }
}

extern "C" void kernel_launch(void* const* d_in, const int* in_sizes, int n_in,
                              void* d_out, int out_size, void* d_ws, size_t ws_size,
                              hipStream_t stream) {
    const int* src = (const int*)d_in[0];
    const unsigned char* pad = (const unsigned char*)d_in[1];
    const float* emb = (const float*)d_in[2];
    const float* cls_token = (const float*)d_in[3];
    const float* qkv_w = (const float*)d_in[4];
    const float* qkv_b = (const float*)d_in[5];
    const float* out_w = (const float*)d_in[6];
    const float* out_b = (const float*)d_in[7];
    const float* rel_emb = (const float*)d_in[8];
    const float* ln1_g = (const float*)d_in[9];
    const float* ln1_b = (const float*)d_in[10];
    const float* w1 = (const float*)d_in[11];
    const float* b1 = (const float*)d_in[12];
    const float* w2 = (const float*)d_in[13];
    const float* b2 = (const float*)d_in[14];
    const float* ln2_g = (const float*)d_in[15];
    const float* ln2_b = (const float*)d_in[16];
    const float* norm_g = (const float*)d_in[17];
    const float* norm_b = (const float*)d_in[18];
    const float* cls_w = (const float*)d_in[19];
    const float* cls_b = (const float*)d_in[20];
    float* out = (float*)d_out;

    char* ws = (char*)d_ws;
    size_t off = 0;
    float* x   = (float*)(ws + off); off += (size_t)MP * D * 4;
    bf16*  xb  = (bf16*) (ws + off); off += (size_t)MP * D * 2;
    float* x2  = (float*)(ws + off); off += (size_t)MP * D * 4;
    bf16*  x2b = (bf16*) (ws + off); off += (size_t)MP * D * 2;
    char*  R   = ws + off;           off += (size_t)MP * 3 * D * 4; // qkvb | (hb + p)
    bf16*  qkvb = (bf16*)R;                              // MP*3D*2
    bf16*  hb  = (bf16*)R;                               // MP*FF*2 (after attn)
    float* p   = (float*)(R + (size_t)MP * FF * 2);      // MP*D*4
    bf16*  obf = (bf16*) (ws + off); off += (size_t)MP * D * 2;

    const size_t WQ = (size_t)NL * 3 * D * D;
    const size_t WO = (size_t)NL * D * D;
    const size_t W1E = (size_t)NL * FF * D;
    const size_t W2E = (size_t)NL * D * FF;
    const size_t WALL = WQ + WO + W1E + W2E;
    bool all_w = (off + WALL * 2) <= ws_size;

    bf16 *wq_a = nullptr, *wo_a = nullptr, *w1_a = nullptr, *w2_a = nullptr, *wbuf = nullptr;
    if (all_w) {
        wq_a = (bf16*)(ws + off);
        wo_a = wq_a + WQ;
        w1_a = wo_a + WO;
        w2_a = w1_a + W1E;
        int n4;
        n4 = (int)(WQ / 4);  cvt_k<<<dim3((n4 + 255) / 256), 256, 0, stream>>>(qkv_w, wq_a, n4);
        n4 = (int)(WO / 4);  cvt_k<<<dim3((n4 + 255) / 256), 256, 0, stream>>>(out_w, wo_a, n4);
        n4 = (int)(W1E / 4); cvt_k<<<dim3((n4 + 255) / 256), 256, 0, stream>>>(w1, w1_a, n4);
        n4 = (int)(W2E / 4); cvt_k<<<dim3((n4 + 255) / 256), 256, 0, stream>>>(w2, w2_a, n4);
    } else {
        wbuf = (bf16*)(ws + off); // per-layer rotating buffer
    }

    const int M = B * L;
    {
        long total = (long)B * L * D;
        embed_k<<<dim3((unsigned)((total + 255) / 256)), 256, 0, stream>>>(src, emb, cls_token, x, xb);
    }
    for (int l = 0; l < NL; l++) {
        const float* qb  = qkv_b + (size_t)l * 3 * D;
        const float* obi = out_b + (size_t)l * D;
        const float* re  = rel_emb + (size_t)l * (2 * MAXD + 1) * H;
        const float* g1  = ln1_g + (size_t)l * D;
        const float* be1 = ln1_b + (size_t)l * D;
        const float* B1p = b1 + (size_t)l * FF;
        const float* B2p = b2 + (size_t)l * D;
        const float* g2  = ln2_g + (size_t)l * D;
        const float* be2 = ln2_b + (size_t)l * D;

        const bf16 *wqb, *wob, *w1b, *w2b;
        if (all_w) {
            wqb = wq_a + (size_t)l * 3 * D * D;
            wob = wo_a + (size_t)l * D * D;
            w1b = w1_a + (size_t)l * FF * D;
            w2b = w2_a + (size_t)l * D * FF;
        } else {
            bf16* wp_ = wbuf;
            wqb = wp_;            wp_ += 3 * D * D;
            wob = wp_;            wp_ += D * D;
            w1b = wp_;            wp_ += FF * D;
            w2b = wp_;
            int n4;
            n4 = 3 * D * D / 4; cvt_k<<<dim3((n4 + 255) / 256), 256, 0, stream>>>(qkv_w + (size_t)l * 3 * D * D, (bf16*)wqb, n4);
            n4 = D * D / 4;     cvt_k<<<dim3((n4 + 255) / 256), 256, 0, stream>>>(out_w + (size_t)l * D * D, (bf16*)wob, n4);
            n4 = FF * D / 4;    cvt_k<<<dim3((n4 + 255) / 256), 256, 0, stream>>>(w1 + (size_t)l * FF * D, (bf16*)w1b, n4);
            n4 = D * FF / 4;    cvt_k<<<dim3((n4 + 255) / 256), 256, 0, stream>>>(w2 + (size_t)l * D * FF, (bf16*)w2b, n4);
        }

        mgemm<0, 1, 1, 128><<<dim3(3 * D / 128, MP / 128), 256, 0, stream>>>(xb, wqb, qb, nullptr, qkvb, 3 * D, D, D);
        fattn_k<<<dim3(B * H, 9), 256, 0, stream>>>(qkvb, re, pad, obf);
        mgemm<0, 0, 1, 64><<<dim3(D / 128, MP / 64), 256, 0, stream>>>(obf, wob, obi, p, nullptr, D, D, D);
        add_ln_k<<<dim3(M), 256, 0, stream>>>(x, p, g1, be1, x2, x2b);
        mgemm<1, 1, 1, 128><<<dim3(FF / 128, MP / 128), 256, 0, stream>>>(x2b, w1b, B1p, nullptr, hb, FF, D, D);
        mgemm<0, 0, 1, 64><<<dim3(D / 128, MP / 64), 256, 0, stream>>>(hb, w2b, B2p, p, nullptr, D, FF, FF);
        add_ln_k<<<dim3(M), 256, 0, stream>>>(x2, p, g2, be2, x, xb);
    }
    cls_k<<<dim3(B), 256, 0, stream>>>(x, norm_g, norm_b, cls_w, cls_b, out);
}